// Round 11
// baseline (535.007 us; speedup 1.0000x reference)
//
#include <hip/hip_runtime.h>
#include <hip/hip_fp16.h>

#define N_TOTAL 194048
#define NE      3104768
#define HID     64
#define NNODES  1516
#define CIN     32
#define FIN     97024
#define EPS     1e-5f
#define NBUCK   758          // N_TOTAL / 256
#define NBLKC   1024         // edge-chunk blocks (round-8 proven config)
#define CHUNK   3032         // NE / NBLKC
#define FBLK    379          // FIN / 256
#define FCHUNK  256

using f16x8 = __attribute__((ext_vector_type(8))) _Float16;
using f32x4 = __attribute__((ext_vector_type(4))) float;

__device__ inline uint f2u(float a, float b){
    __half2 h = __floats2half2_rn(a, b);
    return *(const uint*)&h;
}
__device__ inline float2 u2f(uint u){
    __half2 h = *(const __half2*)&u;
    return __half22float2(h);
}

// ================= bucketed CSR build (round-8 proven, no global atomics) =================
__global__ __launch_bounds__(256) void k_bktA(const int* __restrict__ col,
                                              int* __restrict__ blkhist){
    __shared__ int hist[NBUCK];
    int t = threadIdx.x;
    for (int i = t; i < NBUCK; i += 256) hist[i] = 0;
    __syncthreads();
    int base = blockIdx.x*CHUNK;
    for (int e = base + t; e < base + CHUNK; e += 256)
        atomicAdd(&hist[col[e] >> 8], 1);
    __syncthreads();
    for (int i = t; i < NBUCK; i += 256)
        blkhist[i*NBLKC + blockIdx.x] = hist[i];
}

__global__ __launch_bounds__(256) void k_bktB1(const int* __restrict__ blkhist,
                                               int* __restrict__ blkoff,
                                               int* __restrict__ btot){
    int b = blockIdx.x, t = threadIdx.x;
    const int* src = blkhist + (size_t)b*NBLKC;
    int4 v = *(const int4*)(src + t*4);
    int s0 = v.x, s1 = s0 + v.y, s2 = s1 + v.z, s3 = s2 + v.w;
    __shared__ int s[256];
    s[t] = s3; __syncthreads();
    for (int off = 1; off < 256; off <<= 1){
        int u = (t >= off) ? s[t-off] : 0;
        __syncthreads();
        s[t] += u;
        __syncthreads();
    }
    int ex = s[t] - s3;
    int* dst = blkoff + (size_t)b*NBLKC + t*4;
    dst[0] = ex; dst[1] = ex + s0; dst[2] = ex + s1; dst[3] = ex + s2;
    if (t == 255) btot[b] = ex + s3;
}

__global__ __launch_bounds__(256) void k_bktB2(const int* __restrict__ btot, int* __restrict__ bstart){
    __shared__ int s[256];
    int t = threadIdx.x;
    int i0 = t*3;
    int a = (i0   < NBUCK) ? btot[i0]   : 0;
    int b = (i0+1 < NBUCK) ? btot[i0+1] : 0;
    int c = (i0+2 < NBUCK) ? btot[i0+2] : 0;
    int tot = a+b+c;
    s[t] = tot; __syncthreads();
    for (int off = 1; off < 256; off <<= 1){
        int u = (t >= off) ? s[t-off] : 0;
        __syncthreads();
        s[t] += u;
        __syncthreads();
    }
    int ex = s[t] - tot;
    if (i0   < NBUCK) bstart[i0]   = ex;
    if (i0+1 < NBUCK) bstart[i0+1] = ex + a;
    if (i0+2 < NBUCK) bstart[i0+2] = ex + a + b;
}

__global__ __launch_bounds__(256) void k_bktC(const int* __restrict__ row, const int* __restrict__ col,
                                              const float* __restrict__ w,
                                              const int* __restrict__ blkoff,
                                              const int* __restrict__ bstart,
                                              int2* __restrict__ pairsB){
    __shared__ int lbase[NBUCK];
    __shared__ int lrank[NBUCK];
    int t = threadIdx.x;
    for (int i = t; i < NBUCK; i += 256){
        lbase[i] = bstart[i] + blkoff[(size_t)i*NBLKC + blockIdx.x];
        lrank[i] = 0;
    }
    __syncthreads();
    int base = blockIdx.x*CHUNK;
    for (int e = base + t; e < base + CHUNK; e += 256){
        int c = col[e];
        int b = c >> 8;
        int rk = atomicAdd(&lrank[b], 1);
        pairsB[lbase[b] + rk] = make_int2(row[e] | ((c & 255) << 18), __float_as_int(w[e]));
    }
}

__global__ __launch_bounds__(256) void k_bktD(const int2* __restrict__ pairsB,
                                              const int* __restrict__ bstart,
                                              const int* __restrict__ btot,
                                              int* __restrict__ startv, int* __restrict__ cnt,
                                              float* __restrict__ dinv,
                                              int2* __restrict__ pairs){
    __shared__ int   nh[256];
    __shared__ float ws[256];
    __shared__ int   noff[256];
    __shared__ int   sc[256];
    int b = blockIdx.x, t = threadIdx.x;
    nh[t] = 0; ws[t] = 0.f;
    __syncthreads();
    int s0 = bstart[b];
    int n  = btot[b];
    for (int e = s0 + t; e < s0 + n; e += 256){
        int2 p = pairsB[e];
        int lo = (p.x >> 18) & 255;
        atomicAdd(&nh[lo], 1);
        atomicAdd(&ws[lo], __int_as_float(p.y));
    }
    __syncthreads();
    int my = nh[t];
    sc[t] = my; __syncthreads();
    for (int off = 1; off < 256; off <<= 1){
        int u = (t >= off) ? sc[t-off] : 0;
        __syncthreads();
        sc[t] += u;
        __syncthreads();
    }
    int ex = sc[t] - my;
    noff[t] = s0 + ex;
    int node = b*256 + t;
    startv[node] = s0 + ex;
    cnt[node]    = my;
    dinv[node]   = rsqrtf(1.0f + ws[t]);
    nh[t] = 0;
    __syncthreads();
    for (int e = s0 + t; e < s0 + n; e += 256){
        int2 p = pairsB[e];
        int lo = (p.x >> 18) & 255;
        int rk = atomicAdd(&nh[lo], 1);
        pairs[noff[lo] + rk] = make_int2(p.x & 0x3FFFF, p.y);
    }
}

__global__ __launch_bounds__(256) void k_norm(int2* __restrict__ pairs, const float* __restrict__ dinv){
    int s0 = (blockIdx.x*256 + threadIdx.x)*4;
    int4 a = *(const int4*)(pairs + s0);
    int4 b = *(const int4*)(pairs + s0 + 2);
    float d0 = dinv[a.x], d1 = dinv[a.z], d2 = dinv[b.x], d3 = dinv[b.z];
    a.y = __float_as_int(__int_as_float(a.y) * d0);
    a.w = __float_as_int(__int_as_float(a.w) * d1);
    b.y = __float_as_int(__int_as_float(b.y) * d2);
    b.w = __float_as_int(__int_as_float(b.w) * d3);
    *(int4*)(pairs + s0)     = a;
    *(int4*)(pairs + s0 + 2) = b;
}

// ---------------- transpose x [B][32][1516] -> xh fp16 [N][32] ----------------
__global__ __launch_bounds__(256) void k_prep1(const float* __restrict__ x, __half* __restrict__ xh){
    int idx = blockIdx.x*256 + threadIdx.x;
    if (idx >= N_TOTAL) return;
    int b = idx / NNODES, nn = idx - b*NNODES;
    const float* xp = x + (size_t)b*CIN*NNODES + nn;
    uint u[16];
    #pragma unroll
    for (int c2 = 0; c2 < 16; ++c2){
        float a0 = xp[(size_t)(2*c2)*NNODES];
        float a1 = xp[(size_t)(2*c2+1)*NNODES];
        u[c2] = f2u(a0, a1);
    }
    uint4* dst = (uint4*)(xh + (size_t)idx*CIN);
    dst[0] = make_uint4(u[0], u[1], u[2],  u[3]);
    dst[1] = make_uint4(u[4], u[5], u[6],  u[7]);
    dst[2] = make_uint4(u[8], u[9], u[10], u[11]);
    dst[3] = make_uint4(u[12],u[13],u[14], u[15]);
}

// ---------------- W fp32 -> fp16 (layer weights) ----------------
__global__ __launch_bounds__(256) void k_prepW(const float* __restrict__ W1, const float* __restrict__ W2,
                                               const float* __restrict__ W3,
                                               __half* __restrict__ Wh1, __half* __restrict__ Wh2,
                                               __half* __restrict__ Wh3){
    int t = blockIdx.x*256 + threadIdx.x;
    if (t < 2048) Wh1[t] = __float2half(W1[t]);
    if (t < 4096){ Wh2[t] = __float2half(W2[t]); Wh3[t] = __float2half(W3[t]); }
}

// ---------------- CSR gather, 8-deep MLP, optional fused BN+ReLU ----------------
template<bool BN>
__device__ inline void acc4(float n, uint2 u, const float4& sc, const float4& sh,
                            float& a0, float& a1, float& a2, float& a3){
    float2 lo = u2f(u.x), hi = u2f(u.y);
    float v0, v1, v2, v3;
    if (BN){
        v0 = fmaxf(0.f, lo.x*sc.x + sh.x); v1 = fmaxf(0.f, lo.y*sc.y + sh.y);
        v2 = fmaxf(0.f, hi.x*sc.z + sh.z); v3 = fmaxf(0.f, hi.y*sc.w + sh.w);
    } else { v0 = lo.x; v1 = lo.y; v2 = hi.x; v3 = hi.y; }
    a0 += n*v0; a1 += n*v1; a2 += n*v2; a3 += n*v3;
}

template<int F, bool BN>
__global__ __launch_bounds__(256) void k_gatherH(const __half* __restrict__ h,
                                                 const float* __restrict__ dinv,
                                                 const int* __restrict__ startv,
                                                 const int* __restrict__ cnt,
                                                 const int2* __restrict__ pairs,
                                                 const float* __restrict__ scale,
                                                 const float* __restrict__ shift,
                                                 __half* __restrict__ agg){
    constexpr int LPN = F/4;
    int node = blockIdx.x*(256/LPN) + threadIdx.x/LPN;
    int q    = (threadIdx.x % LPN)*4;
    const __half* hq = h + q;
    float4 sc = make_float4(0,0,0,0), sh = make_float4(0,0,0,0);
    if (BN){ sc = *(const float4*)(scale + q); sh = *(const float4*)(shift + q); }
    float a0 = 0.f, a1 = 0.f, a2 = 0.f, a3 = 0.f;

    int s = startv[node];
    int e = s + cnt[node];
    for (; s + 8 <= e; s += 8){
        int2 p0 = pairs[s],   p1 = pairs[s+1], p2 = pairs[s+2], p3 = pairs[s+3];
        int2 p4 = pairs[s+4], p5 = pairs[s+5], p6 = pairs[s+6], p7 = pairs[s+7];
        uint2 u0 = *(const uint2*)(hq + (size_t)p0.x*F);
        uint2 u1 = *(const uint2*)(hq + (size_t)p1.x*F);
        uint2 u2v= *(const uint2*)(hq + (size_t)p2.x*F);
        uint2 u3 = *(const uint2*)(hq + (size_t)p3.x*F);
        uint2 u4 = *(const uint2*)(hq + (size_t)p4.x*F);
        uint2 u5 = *(const uint2*)(hq + (size_t)p5.x*F);
        uint2 u6 = *(const uint2*)(hq + (size_t)p6.x*F);
        uint2 u7 = *(const uint2*)(hq + (size_t)p7.x*F);
        acc4<BN>(__int_as_float(p0.y), u0,  sc, sh, a0, a1, a2, a3);
        acc4<BN>(__int_as_float(p1.y), u1,  sc, sh, a0, a1, a2, a3);
        acc4<BN>(__int_as_float(p2.y), u2v, sc, sh, a0, a1, a2, a3);
        acc4<BN>(__int_as_float(p3.y), u3,  sc, sh, a0, a1, a2, a3);
        acc4<BN>(__int_as_float(p4.y), u4,  sc, sh, a0, a1, a2, a3);
        acc4<BN>(__int_as_float(p5.y), u5,  sc, sh, a0, a1, a2, a3);
        acc4<BN>(__int_as_float(p6.y), u6,  sc, sh, a0, a1, a2, a3);
        acc4<BN>(__int_as_float(p7.y), u7,  sc, sh, a0, a1, a2, a3);
    }
    for (; s + 4 <= e; s += 4){
        int2 p0 = pairs[s], p1 = pairs[s+1], p2 = pairs[s+2], p3 = pairs[s+3];
        uint2 u0 = *(const uint2*)(hq + (size_t)p0.x*F);
        uint2 u1 = *(const uint2*)(hq + (size_t)p1.x*F);
        uint2 u2v= *(const uint2*)(hq + (size_t)p2.x*F);
        uint2 u3 = *(const uint2*)(hq + (size_t)p3.x*F);
        acc4<BN>(__int_as_float(p0.y), u0,  sc, sh, a0, a1, a2, a3);
        acc4<BN>(__int_as_float(p1.y), u1,  sc, sh, a0, a1, a2, a3);
        acc4<BN>(__int_as_float(p2.y), u2v, sc, sh, a0, a1, a2, a3);
        acc4<BN>(__int_as_float(p3.y), u3,  sc, sh, a0, a1, a2, a3);
    }
    for (; s < e; ++s){
        int2 p0 = pairs[s];
        uint2 u0 = *(const uint2*)(hq + (size_t)p0.x*F);
        acc4<BN>(__int_as_float(p0.y), u0, sc, sh, a0, a1, a2, a3);
    }
    float di = dinv[node];
    a0 *= di; a1 *= di; a2 *= di; a3 *= di;
    uint2 us = *(const uint2*)(hq + (size_t)node*F);
    acc4<BN>(di*di, us, sc, sh, a0, a1, a2, a3);   // self-loop term
    *(uint2*)(agg + (size_t)node*F + q) = make_uint2(f2u(a0,a1), f2u(a2,a3));
}

// ---------------- MFMA GEMM: out fp16 [n][64] = agg[n][K](fp16) @ Wh[64][K]^T + b ----------------
template<int K>
__global__ __launch_bounds__(256) void k_gemmMF(const __half* __restrict__ hin,
                                                const __half* __restrict__ Wh,
                                                const float* __restrict__ bias,
                                                __half* __restrict__ out){
    __shared__ __align__(16) __half lds[4][16][72];
    int t = threadIdx.x;
    int wv = t >> 6, l = t & 63;
    int lr = l & 15, lk = (l >> 4) * 8;
    int node0 = blockIdx.x*64 + wv*16;

    f16x8 a0 = *(const f16x8*)(hin + (size_t)(node0 + lr)*K + lk);
    f16x8 a1;
    if (K == 64) a1 = *(const f16x8*)(hin + (size_t)(node0 + lr)*K + 32 + lk);

    f32x4 acc[4];
    #pragma unroll
    for (int tt = 0; tt < 4; ++tt){
        f16x8 b0 = *(const f16x8*)(Wh + (size_t)(tt*16 + lr)*K + lk);
        acc[tt] = (f32x4){0.f, 0.f, 0.f, 0.f};
        acc[tt] = __builtin_amdgcn_mfma_f32_16x16x32_f16(a0, b0, acc[tt], 0, 0, 0);
        if (K == 64){
            f16x8 b1 = *(const f16x8*)(Wh + (size_t)(tt*16 + lr)*K + 32 + lk);
            acc[tt] = __builtin_amdgcn_mfma_f32_16x16x32_f16(a1, b1, acc[tt], 0, 0, 0);
        }
    }
    #pragma unroll
    for (int tt = 0; tt < 4; ++tt){
        float bb = bias[tt*16 + lr];
        #pragma unroll
        for (int r = 0; r < 4; ++r)
            lds[wv][(l>>4)*4 + r][tt*16 + lr] = __float2half(acc[tt][r] + bb);
    }
    int rr = l >> 2, cc = (l & 3)*16;
    uint4 v0 = *(const uint4*)(&lds[wv][rr][cc]);
    uint4 v1 = *(const uint4*)(&lds[wv][rr][cc + 8]);
    *(uint4*)(out + (size_t)(node0 + rr)*64 + cc)     = v0;
    *(uint4*)(out + (size_t)(node0 + rr)*64 + cc + 8) = v1;
}

// ---------------- BN stats over node axis (fp16 input) ----------------
__global__ __launch_bounds__(256) void k_bn_reduce(const __half* __restrict__ x, float* gsum, float* gsq){
    int t = threadIdx.x;
    int f = t & 63, g4 = t >> 6;
    float s = 0.f, q = 0.f;
    for (int i = blockIdx.x*4 + g4; i < N_TOTAL; i += gridDim.x*4){
        float v = __half2float(x[(size_t)i*64 + f]);
        s += v; q += v*v;
    }
    __shared__ float sh[2][4][64];
    sh[0][g4][f] = s; sh[1][g4][f] = q;
    __syncthreads();
    if (t < 64){
        float ss = sh[0][0][t] + sh[0][1][t] + sh[0][2][t] + sh[0][3][t];
        float qq = sh[1][0][t] + sh[1][1][t] + sh[1][2][t] + sh[1][3][t];
        atomicAdd(&gsum[t], ss);
        atomicAdd(&gsq[t],  qq);
    }
}

__global__ void k_bn_final(const float* __restrict__ gsum, const float* __restrict__ gsq,
                           const float* __restrict__ g, const float* __restrict__ be,
                           float* scale, float* shift){
    int f = threadIdx.x;
    if (f < 64){
        float mean = gsum[f] / (float)N_TOTAL;
        float var  = gsq[f] / (float)N_TOTAL - mean*mean;
        float sc   = g[f] / sqrtf(var + EPS);
        scale[f] = sc;
        shift[f] = be[f] - mean*sc;
    }
}

// ---------------- FC1 on MFMA: C = relu(bn(A))(fp16) @ Wl1^T, split-K ----------------
__device__ inline f16x8 bn8(f16x8 v, const float4& s0, const float4& s1,
                            const float4& h0, const float4& h1){
    uint4 u = *(uint4*)&v;
    float2 p0 = u2f(u.x), p1 = u2f(u.y), p2 = u2f(u.z), p3 = u2f(u.w);
    float r0 = fmaxf(0.f, p0.x*s0.x + h0.x);
    float r1 = fmaxf(0.f, p0.y*s0.y + h0.y);
    float r2 = fmaxf(0.f, p1.x*s0.z + h0.z);
    float r3 = fmaxf(0.f, p1.y*s0.w + h0.w);
    float r4 = fmaxf(0.f, p2.x*s1.x + h1.x);
    float r5 = fmaxf(0.f, p2.y*s1.y + h1.y);
    float r6 = fmaxf(0.f, p3.x*s1.z + h1.z);
    float r7 = fmaxf(0.f, p3.y*s1.w + h1.w);
    uint4 o = make_uint4(f2u(r0,r1), f2u(r2,r3), f2u(r4,r5), f2u(r6,r7));
    return *(f16x8*)&o;
}

__global__ __launch_bounds__(256) void k_fc1MF(const __half* __restrict__ A,
                                               const float* __restrict__ Wl1,
                                               const float* __restrict__ scale,
                                               const float* __restrict__ shift,
                                               float* __restrict__ part){
    __shared__ __align__(16) __half Bh[128][264];
    int t = threadIdx.x;
    int kbase = blockIdx.x * FCHUNK;
    #pragma unroll
    for (int i = 0; i < 32; ++i){
        int flat = i*1024 + t*4;
        int r = flat >> 8, k = flat & 255;
        float4 w = *(const float4*)(Wl1 + (size_t)r*FIN + kbase + k);
        *(uint2*)(&Bh[r][k]) = make_uint2(f2u(w.x, w.y), f2u(w.z, w.w));
    }

    int wv = t >> 6, l = t & 63;
    int lr = l & 15, lk = (l >> 4)*8;
    float4 sc_e0 = *(const float4*)(scale + lk),      sc_e1 = *(const float4*)(scale + lk + 4);
    float4 sc_o0 = *(const float4*)(scale + 32 + lk), sc_o1 = *(const float4*)(scale + 36 + lk);
    float4 sh_e0 = *(const float4*)(shift + lk),      sh_e1 = *(const float4*)(shift + lk + 4);
    float4 sh_o0 = *(const float4*)(shift + 32 + lk), sh_o1 = *(const float4*)(shift + 36 + lk);

    const __half* Ar0 = A + (size_t)(wv*32 + lr)*FIN + kbase + lk;
    const __half* Ar1 = A + (size_t)(wv*32 + 16 + lr)*FIN + kbase + lk;

    f32x4 acc[2][8];
    #pragma unroll
    for (int m = 0; m < 2; ++m)
        #pragma unroll
        for (int n = 0; n < 8; ++n) acc[m][n] = (f32x4){0.f, 0.f, 0.f, 0.f};

    __syncthreads();
    #pragma unroll
    for (int kk = 0; kk < 8; ++kk){
        int ko = kk*32;
        f16x8 a0 = *(const f16x8*)(Ar0 + ko);
        f16x8 a1 = *(const f16x8*)(Ar1 + ko);
        if (kk & 1){
            a0 = bn8(a0, sc_o0, sc_o1, sh_o0, sh_o1);
            a1 = bn8(a1, sc_o0, sc_o1, sh_o0, sh_o1);
        } else {
            a0 = bn8(a0, sc_e0, sc_e1, sh_e0, sh_e1);
            a1 = bn8(a1, sc_e0, sc_e1, sh_e0, sh_e1);
        }
        #pragma unroll
        for (int n = 0; n < 8; ++n){
            f16x8 b = *(const f16x8*)(&Bh[n*16 + lr][ko + lk]);
            acc[0][n] = __builtin_amdgcn_mfma_f32_16x16x32_f16(a0, b, acc[0][n], 0, 0, 0);
            acc[1][n] = __builtin_amdgcn_mfma_f32_16x16x32_f16(a1, b, acc[1][n], 0, 0, 0);
        }
    }
    float* pp = part + (size_t)blockIdx.x*16384;
    #pragma unroll
    for (int m = 0; m < 2; ++m)
        #pragma unroll
        for (int n = 0; n < 8; ++n)
            #pragma unroll
            for (int r = 0; r < 4; ++r)
                pp[(wv*32 + m*16 + (l>>4)*4 + r)*128 + n*16 + lr] = acc[m][n][r];
}

// ---- two-stage split-K reduce ----
__global__ __launch_bounds__(256) void k_fc1_red1(const float* __restrict__ part,
                                                  float* __restrict__ part2){
    int idx = (blockIdx.x & 63)*256 + threadIdx.x;
    int seg = blockIdx.x >> 6;
    int k0 = seg*24;
    int k1 = k0 + 24 < FBLK ? k0 + 24 : FBLK;
    float s = 0.f;
    for (int kc = k0; kc < k1; ++kc) s += part[(size_t)kc*16384 + idx];
    part2[(size_t)seg*16384 + idx] = s;
}

__global__ __launch_bounds__(256) void k_fc1_red2(const float* __restrict__ part2,
                                                  const float* __restrict__ bl1,
                                                  float* __restrict__ C){
    int idx = blockIdx.x*256 + threadIdx.x;
    float s = 0.f;
    #pragma unroll
    for (int i = 0; i < 16; ++i) s += part2[(size_t)i*16384 + idx];
    C[idx] = s + bl1[idx & 127];
}

__global__ void k_fc_stats(const float* __restrict__ C, const float* __restrict__ g,
                           const float* __restrict__ be, float* scale2, float* shift2){
    int j = threadIdx.x;
    if (j < 128){
        float s = 0.f, q = 0.f;
        for (int b = 0; b < 128; ++b){ float v = C[b*128 + j]; s += v; q += v*v; }
        float mean = s / 128.f;
        float var  = q / 128.f - mean*mean;
        float sc   = g[j] / sqrtf(var + EPS);
        scale2[j] = sc;
        shift2[j] = be[j] - mean*sc;
    }
}

__global__ __launch_bounds__(256) void k_fc2(const float* __restrict__ C, const float* __restrict__ scale2,
                                             const float* __restrict__ shift2, const float* __restrict__ Wl3,
                                             const float* __restrict__ bl3, float* __restrict__ out){
    int id = blockIdx.x*256 + threadIdx.x;
    if (id < 1280){
        int b = id / 10, c = id - b*10;
        float acc = bl3[c];
        for (int j = 0; j < 128; ++j){
            float hv = fmaxf(0.f, C[b*128 + j]*scale2[j] + shift2[j]);
            acc += hv * Wl3[c*128 + j];
        }
        out[id] = acc;
    }
}

// ---------------- launch ----------------
extern "C" void kernel_launch(void* const* d_in, const int* in_sizes, int n_in,
                              void* d_out, int out_size, void* d_ws, size_t ws_size,
                              hipStream_t stream){
    const float* x   = (const float*)d_in[0];
    const int*   ei  = (const int*)  d_in[1];
    const float* ew  = (const float*)d_in[2];
    const float* W1  = (const float*)d_in[3];
    const float* b1  = (const float*)d_in[4];
    const float* W2  = (const float*)d_in[5];
    const float* b2  = (const float*)d_in[6];
    const float* W3  = (const float*)d_in[7];
    const float* b3  = (const float*)d_in[8];
    const float* g1  = (const float*)d_in[9];
    const float* be1 = (const float*)d_in[10];
    const float* g2  = (const float*)d_in[11];
    const float* be2 = (const float*)d_in[12];
    const float* g3  = (const float*)d_in[13];
    const float* be3 = (const float*)d_in[14];
    const float* Wl1 = (const float*)d_in[15];
    const float* bl1 = (const float*)d_in[16];
    const float* gl1 = (const float*)d_in[17];
    const float* bel1= (const float*)d_in[18];
    const float* Wl3 = (const float*)d_in[19];
    const float* bl3 = (const float*)d_in[20];
    const int* row = ei;
    const int* col = ei + NE;

    char* p = (char*)d_ws;
    auto alloc = [&](size_t bytes)->char*{
        char* r = p; p += (bytes + 255) & ~(size_t)255; return r;
    };
    float*  bufB     = (float*)alloc((size_t)FBLK*16384*4);     // agg scratch / FC1 partials
    float*  part2    = (float*)alloc((size_t)16*16384*4);
    __half* hpre     = (__half*)alloc((size_t)N_TOTAL*64*2);
    __half* xh       = (__half*)alloc((size_t)N_TOTAL*32*2);
    float*  dinv     = (float*)alloc(N_TOTAL*4);
    int*    cnt      = (int*)  alloc(N_TOTAL*4);
    int*    startv   = (int*)  alloc(N_TOTAL*4);
    int2*   pairsB   = (int2*) alloc((size_t)NE*8);
    int2*   pairs    = (int2*) alloc((size_t)NE*8);
    int*    blkhist  = (int*)  alloc((size_t)NBUCK*NBLKC*4);
    int*    blkoff   = (int*)  alloc((size_t)NBUCK*NBLKC*4);
    int*    btot     = (int*)  alloc(NBUCK*4);
    int*    bstart   = (int*)  alloc(NBUCK*4);
    __half* Wh1      = (__half*)alloc(2048*2);
    __half* Wh2      = (__half*)alloc(4096*2);
    __half* Wh3      = (__half*)alloc(4096*2);
    float*  gsum     = (float*)alloc(256);
    float*  gsq      = (float*)alloc(256);
    float*  scale1   = (float*)alloc(256);
    float*  shift1   = (float*)alloc(256);
    float*  scale2l  = (float*)alloc(256);
    float*  shift2l  = (float*)alloc(256);
    float*  scale3   = (float*)alloc(256);
    float*  shift3   = (float*)alloc(256);
    float*  Cfc      = (float*)alloc(65536);
    float*  scaleF   = (float*)alloc(512);
    float*  shiftF   = (float*)alloc(512);
    __half* agg32    = (__half*)bufB;
    __half* agg64    = (__half*)bufB;

    const int NB_N  = 758;     // N_TOTAL/256
    const int NB_E4 = 3032;    // NE/4/256
    k_prepW<<<16,    256, 0, stream>>>(W1, W2, W3, Wh1, Wh2, Wh3);
    k_bktA <<<NBLKC, 256, 0, stream>>>(col, blkhist);
    k_bktB1<<<NBUCK, 256, 0, stream>>>(blkhist, blkoff, btot);
    k_bktB2<<<1,     256, 0, stream>>>(btot, bstart);
    k_bktC <<<NBLKC, 256, 0, stream>>>(row, col, ew, blkoff, bstart, pairsB);
    k_bktD <<<NBUCK, 256, 0, stream>>>(pairsB, bstart, btot, startv, cnt, dinv, pairs);
    k_norm <<<NB_E4, 256, 0, stream>>>(pairs, dinv);
    k_prep1<<<NB_N,  256, 0, stream>>>(x, xh);

    // ---- layer 1 (aggregate-first, 32-dim fp16) ----
    k_gatherH<32,false><<<6064, 256, 0, stream>>>(xh, dinv, startv, cnt, pairs, nullptr, nullptr, agg32);
    k_gemmMF<32>       <<<3032, 256, 0, stream>>>(agg32, Wh1, b1, hpre);
    hipMemsetAsync(gsum, 0, 512, stream);
    k_bn_reduce        <<<1024, 256, 0, stream>>>(hpre, gsum, gsq);
    k_bn_final         <<<1, 64, 0, stream>>>(gsum, gsq, g1, be1, scale1, shift1);
    // ---- layer 2 (BN1+ReLU fused into gather) ----
    k_gatherH<64,true> <<<12128, 256, 0, stream>>>(hpre, dinv, startv, cnt, pairs, scale1, shift1, agg64);
    k_gemmMF<64>       <<<3032,  256, 0, stream>>>(agg64, Wh2, b2, hpre);
    hipMemsetAsync(gsum, 0, 512, stream);
    k_bn_reduce        <<<1024,  256, 0, stream>>>(hpre, gsum, gsq);
    k_bn_final         <<<1, 64, 0, stream>>>(gsum, gsq, g2, be2, scale2l, shift2l);
    // ---- layer 3 ----
    k_gatherH<64,true> <<<12128, 256, 0, stream>>>(hpre, dinv, startv, cnt, pairs, scale2l, shift2l, agg64);
    k_gemmMF<64>       <<<3032,  256, 0, stream>>>(agg64, Wh3, b3, hpre);
    hipMemsetAsync(gsum, 0, 512, stream);
    k_bn_reduce        <<<1024,  256, 0, stream>>>(hpre, gsum, gsq);
    k_bn_final         <<<1, 64, 0, stream>>>(gsum, gsq, g3, be3, scale3, shift3);

    // ---- FC head (BN3+ReLU fused into FC1 A-fragments, MFMA) ----
    k_fc1MF    <<<FBLK, 256, 0, stream>>>(hpre, Wl1, scale3, shift3, bufB);
    k_fc1_red1 <<<1024, 256, 0, stream>>>(bufB, part2);
    k_fc1_red2 <<<64,   256, 0, stream>>>(part2, bl1, Cfc);
    k_fc_stats <<<1,    128, 0, stream>>>(Cfc, gl1, bel1, scaleF, shiftF);
    k_fc2      <<<5,    256, 0, stream>>>(Cfc, scaleF, shiftF, Wl3, bl3, (float*)d_out);
}

// Round 12
// 522.908 us; speedup vs baseline: 1.0231x; 1.0231x over previous
//
#include <hip/hip_runtime.h>
#include <hip/hip_fp16.h>

#define N_TOTAL 194048
#define NE      3104768
#define HID     64
#define NNODES  1516
#define CIN     32
#define FIN     97024
#define EPS     1e-5f
#define NBUCK   758          // N_TOTAL / 256
#define NBLKC   512          // edge-chunk blocks
#define CHUNK   6064         // NE / NBLKC
#define FBLK    379          // FIN / 256
#define FCHUNK  256

using f16x8 = __attribute__((ext_vector_type(8))) _Float16;
using f32x4 = __attribute__((ext_vector_type(4))) float;

__device__ inline uint f2u(float a, float b){
    __half2 h = __floats2half2_rn(a, b);
    return *(const uint*)&h;
}
__device__ inline float2 u2f(uint u){
    __half2 h = *(const __half2*)&u;
    return __half22float2(h);
}

// ================= bucketed CSR build (no global atomics) =================
__global__ __launch_bounds__(256) void k_bktA(const int* __restrict__ col,
                                              int* __restrict__ blkhist){
    __shared__ int hist[NBUCK];
    int t = threadIdx.x;
    for (int i = t; i < NBUCK; i += 256) hist[i] = 0;
    __syncthreads();
    int base = blockIdx.x*CHUNK;
    for (int e = base + t; e < base + CHUNK; e += 256)
        atomicAdd(&hist[col[e] >> 8], 1);
    __syncthreads();
    for (int i = t; i < NBUCK; i += 256)
        blkhist[i*NBLKC + blockIdx.x] = hist[i];
}

// per bucket: exclusive scan of 512 block counts (2 per thread)
__global__ __launch_bounds__(256) void k_bktB1(const int* __restrict__ blkhist,
                                               int* __restrict__ blkoff,
                                               int* __restrict__ btot){
    int b = blockIdx.x, t = threadIdx.x;
    const int* src = blkhist + (size_t)b*NBLKC;
    int2 v = *(const int2*)(src + t*2);
    int s0 = v.x, s1 = s0 + v.y;
    __shared__ int s[256];
    s[t] = s1; __syncthreads();
    for (int off = 1; off < 256; off <<= 1){
        int u = (t >= off) ? s[t-off] : 0;
        __syncthreads();
        s[t] += u;
        __syncthreads();
    }
    int ex = s[t] - s1;
    int* dst = blkoff + (size_t)b*NBLKC + t*2;
    dst[0] = ex; dst[1] = ex + s0;
    if (t == 255) btot[b] = ex + s1;
}

__global__ __launch_bounds__(256) void k_bktB2(const int* __restrict__ btot, int* __restrict__ bstart){
    __shared__ int s[256];
    int t = threadIdx.x;
    int i0 = t*3;
    int a = (i0   < NBUCK) ? btot[i0]   : 0;
    int b = (i0+1 < NBUCK) ? btot[i0+1] : 0;
    int c = (i0+2 < NBUCK) ? btot[i0+2] : 0;
    int tot = a+b+c;
    s[t] = tot; __syncthreads();
    for (int off = 1; off < 256; off <<= 1){
        int u = (t >= off) ? s[t-off] : 0;
        __syncthreads();
        s[t] += u;
        __syncthreads();
    }
    int ex = s[t] - tot;
    if (i0   < NBUCK) bstart[i0]   = ex;
    if (i0+1 < NBUCK) bstart[i0+1] = ex + a;
    if (i0+2 < NBUCK) bstart[i0+2] = ex + a + b;
}

// Pass C: LDS counting-sort of the block's chunk, then coalesced run write-out.
// Each bucket's ~8-edge run is written by consecutive lanes in one wave op
// -> full-line stores instead of temporally-scattered 8B partials.
__global__ __launch_bounds__(256) void k_bktC(const int* __restrict__ row, const int* __restrict__ col,
                                              const float* __restrict__ w,
                                              const int* __restrict__ blkoff,
                                              const int* __restrict__ bstart,
                                              int2* __restrict__ pairsB){
    __shared__ int2 staged[CHUNK];    // 48.5 KB
    __shared__ int  lbase[NBUCK];
    __shared__ int  locoff[NBUCK];
    __shared__ int  lcur[NBUCK];
    __shared__ int  sc[256];
    int t = threadIdx.x;
    for (int i = t; i < NBUCK; i += 256){
        lbase[i] = bstart[i] + blkoff[(size_t)i*NBLKC + blockIdx.x];
        lcur[i]  = 0;
    }
    __syncthreads();
    int base = blockIdx.x*CHUNK;
    // local histogram
    for (int e = base + t; e < base + CHUNK; e += 256)
        atomicAdd(&lcur[col[e] >> 8], 1);
    __syncthreads();
    // exclusive scan lcur -> locoff (3 per thread)
    int i0 = t*3;
    int a = (i0   < NBUCK) ? lcur[i0]   : 0;
    int b = (i0+1 < NBUCK) ? lcur[i0+1] : 0;
    int c = (i0+2 < NBUCK) ? lcur[i0+2] : 0;
    int tot = a+b+c;
    sc[t] = tot; __syncthreads();
    for (int off = 1; off < 256; off <<= 1){
        int u = (t >= off) ? sc[t-off] : 0;
        __syncthreads();
        sc[t] += u;
        __syncthreads();
    }
    int ex = sc[t] - tot;
    if (i0   < NBUCK) locoff[i0]   = ex;
    if (i0+1 < NBUCK) locoff[i0+1] = ex + a;
    if (i0+2 < NBUCK) locoff[i0+2] = ex + a + b;
    __syncthreads();
    for (int i = t; i < NBUCK; i += 256) lcur[i] = locoff[i];
    __syncthreads();
    // rank-place into staged (bucket-sorted)
    for (int e = base + t; e < base + CHUNK; e += 256){
        int cc = col[e];
        int bb = cc >> 8;
        int rk = atomicAdd(&lcur[bb], 1);
        staged[rk] = make_int2(row[e] | ((cc & 255) << 18), __float_as_int(w[e]));
    }
    __syncthreads();
    // write-out: dest = lbase[b] + (j - locoff[b]); b via binary search (locoff sorted)
    for (int j = t; j < CHUNK; j += 256){
        int lo = 0, hi = NBUCK - 1;
        while (lo < hi){
            int mid = (lo + hi + 1) >> 1;
            if (locoff[mid] <= j) lo = mid; else hi = mid - 1;
        }
        pairsB[lbase[lo] + (j - locoff[lo])] = staged[j];
    }
}

// Pass D1: per-bucket node stats -> startv, cnt, dinv
__global__ __launch_bounds__(256) void k_bktD1(const int2* __restrict__ pairsB,
                                               const int* __restrict__ bstart,
                                               const int* __restrict__ btot,
                                               int* __restrict__ startv, int* __restrict__ cnt,
                                               float* __restrict__ dinv){
    __shared__ int   nh[256];
    __shared__ float ws[256];
    __shared__ int   sc[256];
    int b = blockIdx.x, t = threadIdx.x;
    nh[t] = 0; ws[t] = 0.f;
    __syncthreads();
    int s0 = bstart[b];
    int n  = btot[b];
    for (int e = s0 + t; e < s0 + n; e += 256){
        int2 p = pairsB[e];
        int lo = (p.x >> 18) & 255;
        atomicAdd(&nh[lo], 1);
        atomicAdd(&ws[lo], __int_as_float(p.y));
    }
    __syncthreads();
    int my = nh[t];
    sc[t] = my; __syncthreads();
    for (int off = 1; off < 256; off <<= 1){
        int u = (t >= off) ? sc[t-off] : 0;
        __syncthreads();
        sc[t] += u;
        __syncthreads();
    }
    int ex = sc[t] - my;
    int node = b*256 + t;
    startv[node] = s0 + ex;
    cnt[node]    = my;
    dinv[node]   = rsqrtf(1.0f + ws[t]);
}

// Pass D2: scatter to node-grouped pairs with norm fold (w *= dinv[src]).
// dinv complete after D1 (separate launch); random dinv reads are L2-resident.
__global__ __launch_bounds__(256) void k_bktD2(const int2* __restrict__ pairsB,
                                               const int* __restrict__ bstart,
                                               const int* __restrict__ btot,
                                               const int* __restrict__ startv,
                                               const float* __restrict__ dinv,
                                               int2* __restrict__ pairs){
    __shared__ int sbase[256];
    __shared__ int rank[256];
    int b = blockIdx.x, t = threadIdx.x;
    sbase[t] = startv[b*256 + t];
    rank[t]  = 0;
    __syncthreads();
    int s0 = bstart[b];
    int n  = btot[b];
    for (int e = s0 + t; e < s0 + n; e += 256){
        int2 p = pairsB[e];
        int lo  = (p.x >> 18) & 255;
        int src = p.x & 0x3FFFF;
        float nw = __int_as_float(p.y) * dinv[src];
        int rk = atomicAdd(&rank[lo], 1);
        pairs[sbase[lo] + rk] = make_int2(src, __float_as_int(nw));
    }
}

// ---------------- transpose x [B][32][1516] -> xh fp16 [N][32] ----------------
__global__ __launch_bounds__(256) void k_prep1(const float* __restrict__ x, __half* __restrict__ xh){
    int idx = blockIdx.x*256 + threadIdx.x;
    if (idx >= N_TOTAL) return;
    int b = idx / NNODES, nn = idx - b*NNODES;
    const float* xp = x + (size_t)b*CIN*NNODES + nn;
    uint u[16];
    #pragma unroll
    for (int c2 = 0; c2 < 16; ++c2){
        float a0 = xp[(size_t)(2*c2)*NNODES];
        float a1 = xp[(size_t)(2*c2+1)*NNODES];
        u[c2] = f2u(a0, a1);
    }
    uint4* dst = (uint4*)(xh + (size_t)idx*CIN);
    dst[0] = make_uint4(u[0], u[1], u[2],  u[3]);
    dst[1] = make_uint4(u[4], u[5], u[6],  u[7]);
    dst[2] = make_uint4(u[8], u[9], u[10], u[11]);
    dst[3] = make_uint4(u[12],u[13],u[14], u[15]);
}

// ---------------- W fp32 -> fp16 (layer weights) ----------------
__global__ __launch_bounds__(256) void k_prepW(const float* __restrict__ W1, const float* __restrict__ W2,
                                               const float* __restrict__ W3,
                                               __half* __restrict__ Wh1, __half* __restrict__ Wh2,
                                               __half* __restrict__ Wh3){
    int t = blockIdx.x*256 + threadIdx.x;
    if (t < 2048) Wh1[t] = __float2half(W1[t]);
    if (t < 4096){ Wh2[t] = __float2half(W2[t]); Wh3[t] = __float2half(W3[t]); }
}

// ---------------- CSR gather, 8-deep MLP, optional fused BN+ReLU ----------------
template<bool BN>
__device__ inline void acc4(float n, uint2 u, const float4& sc, const float4& sh,
                            float& a0, float& a1, float& a2, float& a3){
    float2 lo = u2f(u.x), hi = u2f(u.y);
    float v0, v1, v2, v3;
    if (BN){
        v0 = fmaxf(0.f, lo.x*sc.x + sh.x); v1 = fmaxf(0.f, lo.y*sc.y + sh.y);
        v2 = fmaxf(0.f, hi.x*sc.z + sh.z); v3 = fmaxf(0.f, hi.y*sc.w + sh.w);
    } else { v0 = lo.x; v1 = lo.y; v2 = hi.x; v3 = hi.y; }
    a0 += n*v0; a1 += n*v1; a2 += n*v2; a3 += n*v3;
}

template<int F, bool BN>
__global__ __launch_bounds__(256) void k_gatherH(const __half* __restrict__ h,
                                                 const float* __restrict__ dinv,
                                                 const int* __restrict__ startv,
                                                 const int* __restrict__ cnt,
                                                 const int2* __restrict__ pairs,
                                                 const float* __restrict__ scale,
                                                 const float* __restrict__ shift,
                                                 __half* __restrict__ agg){
    constexpr int LPN = F/4;
    int node = blockIdx.x*(256/LPN) + threadIdx.x/LPN;
    int q    = (threadIdx.x % LPN)*4;
    const __half* hq = h + q;
    float4 sc = make_float4(0,0,0,0), sh = make_float4(0,0,0,0);
    if (BN){ sc = *(const float4*)(scale + q); sh = *(const float4*)(shift + q); }
    float a0 = 0.f, a1 = 0.f, a2 = 0.f, a3 = 0.f;

    int s = startv[node];
    int e = s + cnt[node];
    for (; s + 8 <= e; s += 8){
        int2 p0 = pairs[s],   p1 = pairs[s+1], p2 = pairs[s+2], p3 = pairs[s+3];
        int2 p4 = pairs[s+4], p5 = pairs[s+5], p6 = pairs[s+6], p7 = pairs[s+7];
        uint2 u0 = *(const uint2*)(hq + (size_t)p0.x*F);
        uint2 u1 = *(const uint2*)(hq + (size_t)p1.x*F);
        uint2 u2v= *(const uint2*)(hq + (size_t)p2.x*F);
        uint2 u3 = *(const uint2*)(hq + (size_t)p3.x*F);
        uint2 u4 = *(const uint2*)(hq + (size_t)p4.x*F);
        uint2 u5 = *(const uint2*)(hq + (size_t)p5.x*F);
        uint2 u6 = *(const uint2*)(hq + (size_t)p6.x*F);
        uint2 u7 = *(const uint2*)(hq + (size_t)p7.x*F);
        acc4<BN>(__int_as_float(p0.y), u0,  sc, sh, a0, a1, a2, a3);
        acc4<BN>(__int_as_float(p1.y), u1,  sc, sh, a0, a1, a2, a3);
        acc4<BN>(__int_as_float(p2.y), u2v, sc, sh, a0, a1, a2, a3);
        acc4<BN>(__int_as_float(p3.y), u3,  sc, sh, a0, a1, a2, a3);
        acc4<BN>(__int_as_float(p4.y), u4,  sc, sh, a0, a1, a2, a3);
        acc4<BN>(__int_as_float(p5.y), u5,  sc, sh, a0, a1, a2, a3);
        acc4<BN>(__int_as_float(p6.y), u6,  sc, sh, a0, a1, a2, a3);
        acc4<BN>(__int_as_float(p7.y), u7,  sc, sh, a0, a1, a2, a3);
    }
    for (; s + 4 <= e; s += 4){
        int2 p0 = pairs[s], p1 = pairs[s+1], p2 = pairs[s+2], p3 = pairs[s+3];
        uint2 u0 = *(const uint2*)(hq + (size_t)p0.x*F);
        uint2 u1 = *(const uint2*)(hq + (size_t)p1.x*F);
        uint2 u2v= *(const uint2*)(hq + (size_t)p2.x*F);
        uint2 u3 = *(const uint2*)(hq + (size_t)p3.x*F);
        acc4<BN>(__int_as_float(p0.y), u0,  sc, sh, a0, a1, a2, a3);
        acc4<BN>(__int_as_float(p1.y), u1,  sc, sh, a0, a1, a2, a3);
        acc4<BN>(__int_as_float(p2.y), u2v, sc, sh, a0, a1, a2, a3);
        acc4<BN>(__int_as_float(p3.y), u3,  sc, sh, a0, a1, a2, a3);
    }
    for (; s < e; ++s){
        int2 p0 = pairs[s];
        uint2 u0 = *(const uint2*)(hq + (size_t)p0.x*F);
        acc4<BN>(__int_as_float(p0.y), u0, sc, sh, a0, a1, a2, a3);
    }
    float di = dinv[node];
    a0 *= di; a1 *= di; a2 *= di; a3 *= di;
    uint2 us = *(const uint2*)(hq + (size_t)node*F);
    acc4<BN>(di*di, us, sc, sh, a0, a1, a2, a3);   // self-loop term
    *(uint2*)(agg + (size_t)node*F + q) = make_uint2(f2u(a0,a1), f2u(a2,a3));
}

// ---------------- MFMA GEMM: out fp16 [n][64] = agg[n][K](fp16) @ Wh[64][K]^T + b ----------------
template<int K>
__global__ __launch_bounds__(256) void k_gemmMF(const __half* __restrict__ hin,
                                                const __half* __restrict__ Wh,
                                                const float* __restrict__ bias,
                                                __half* __restrict__ out){
    __shared__ __align__(16) __half lds[4][16][72];
    int t = threadIdx.x;
    int wv = t >> 6, l = t & 63;
    int lr = l & 15, lk = (l >> 4) * 8;
    int node0 = blockIdx.x*64 + wv*16;

    f16x8 a0 = *(const f16x8*)(hin + (size_t)(node0 + lr)*K + lk);
    f16x8 a1;
    if (K == 64) a1 = *(const f16x8*)(hin + (size_t)(node0 + lr)*K + 32 + lk);

    f32x4 acc[4];
    #pragma unroll
    for (int tt = 0; tt < 4; ++tt){
        f16x8 b0 = *(const f16x8*)(Wh + (size_t)(tt*16 + lr)*K + lk);
        acc[tt] = (f32x4){0.f, 0.f, 0.f, 0.f};
        acc[tt] = __builtin_amdgcn_mfma_f32_16x16x32_f16(a0, b0, acc[tt], 0, 0, 0);
        if (K == 64){
            f16x8 b1 = *(const f16x8*)(Wh + (size_t)(tt*16 + lr)*K + 32 + lk);
            acc[tt] = __builtin_amdgcn_mfma_f32_16x16x32_f16(a1, b1, acc[tt], 0, 0, 0);
        }
    }
    #pragma unroll
    for (int tt = 0; tt < 4; ++tt){
        float bb = bias[tt*16 + lr];
        #pragma unroll
        for (int r = 0; r < 4; ++r)
            lds[wv][(l>>4)*4 + r][tt*16 + lr] = __float2half(acc[tt][r] + bb);
    }
    int rr = l >> 2, cc = (l & 3)*16;
    uint4 v0 = *(const uint4*)(&lds[wv][rr][cc]);
    uint4 v1 = *(const uint4*)(&lds[wv][rr][cc + 8]);
    *(uint4*)(out + (size_t)(node0 + rr)*64 + cc)     = v0;
    *(uint4*)(out + (size_t)(node0 + rr)*64 + cc + 8) = v1;
}

// ---------------- BN stats over node axis (fp16 input) ----------------
__global__ __launch_bounds__(256) void k_bn_reduce(const __half* __restrict__ x, float* gsum, float* gsq){
    int t = threadIdx.x;
    int f = t & 63, g4 = t >> 6;
    float s = 0.f, q = 0.f;
    for (int i = blockIdx.x*4 + g4; i < N_TOTAL; i += gridDim.x*4){
        float v = __half2float(x[(size_t)i*64 + f]);
        s += v; q += v*v;
    }
    __shared__ float sh[2][4][64];
    sh[0][g4][f] = s; sh[1][g4][f] = q;
    __syncthreads();
    if (t < 64){
        float ss = sh[0][0][t] + sh[0][1][t] + sh[0][2][t] + sh[0][3][t];
        float qq = sh[1][0][t] + sh[1][1][t] + sh[1][2][t] + sh[1][3][t];
        atomicAdd(&gsum[t], ss);
        atomicAdd(&gsq[t],  qq);
    }
}

__global__ void k_bn_final(const float* __restrict__ gsum, const float* __restrict__ gsq,
                           const float* __restrict__ g, const float* __restrict__ be,
                           float* scale, float* shift){
    int f = threadIdx.x;
    if (f < 64){
        float mean = gsum[f] / (float)N_TOTAL;
        float var  = gsq[f] / (float)N_TOTAL - mean*mean;
        float sc   = g[f] / sqrtf(var + EPS);
        scale[f] = sc;
        shift[f] = be[f] - mean*sc;
    }
}

// ---------------- FC1 on MFMA: C = relu(bn(A))(fp16) @ Wl1^T, split-K ----------------
__device__ inline f16x8 bn8(f16x8 v, const float4& s0, const float4& s1,
                            const float4& h0, const float4& h1){
    uint4 u = *(uint4*)&v;
    float2 p0 = u2f(u.x), p1 = u2f(u.y), p2 = u2f(u.z), p3 = u2f(u.w);
    float r0 = fmaxf(0.f, p0.x*s0.x + h0.x);
    float r1 = fmaxf(0.f, p0.y*s0.y + h0.y);
    float r2 = fmaxf(0.f, p1.x*s0.z + h0.z);
    float r3 = fmaxf(0.f, p1.y*s0.w + h0.w);
    float r4 = fmaxf(0.f, p2.x*s1.x + h1.x);
    float r5 = fmaxf(0.f, p2.y*s1.y + h1.y);
    float r6 = fmaxf(0.f, p3.x*s1.z + h1.z);
    float r7 = fmaxf(0.f, p3.y*s1.w + h1.w);
    uint4 o = make_uint4(f2u(r0,r1), f2u(r2,r3), f2u(r4,r5), f2u(r6,r7));
    return *(f16x8*)&o;
}

__global__ __launch_bounds__(256) void k_fc1MF(const __half* __restrict__ A,
                                               const float* __restrict__ Wl1,
                                               const float* __restrict__ scale,
                                               const float* __restrict__ shift,
                                               float* __restrict__ part){
    __shared__ __align__(16) __half Bh[128][264];
    int t = threadIdx.x;
    int kbase = blockIdx.x * FCHUNK;
    #pragma unroll
    for (int i = 0; i < 32; ++i){
        int flat = i*1024 + t*4;
        int r = flat >> 8, k = flat & 255;
        float4 w = *(const float4*)(Wl1 + (size_t)r*FIN + kbase + k);
        *(uint2*)(&Bh[r][k]) = make_uint2(f2u(w.x, w.y), f2u(w.z, w.w));
    }

    int wv = t >> 6, l = t & 63;
    int lr = l & 15, lk = (l >> 4)*8;
    float4 sc_e0 = *(const float4*)(scale + lk),      sc_e1 = *(const float4*)(scale + lk + 4);
    float4 sc_o0 = *(const float4*)(scale + 32 + lk), sc_o1 = *(const float4*)(scale + 36 + lk);
    float4 sh_e0 = *(const float4*)(shift + lk),      sh_e1 = *(const float4*)(shift + lk + 4);
    float4 sh_o0 = *(const float4*)(shift + 32 + lk), sh_o1 = *(const float4*)(shift + 36 + lk);

    const __half* Ar0 = A + (size_t)(wv*32 + lr)*FIN + kbase + lk;
    const __half* Ar1 = A + (size_t)(wv*32 + 16 + lr)*FIN + kbase + lk;

    f32x4 acc[2][8];
    #pragma unroll
    for (int m = 0; m < 2; ++m)
        #pragma unroll
        for (int n = 0; n < 8; ++n) acc[m][n] = (f32x4){0.f, 0.f, 0.f, 0.f};

    __syncthreads();
    #pragma unroll
    for (int kk = 0; kk < 8; ++kk){
        int ko = kk*32;
        f16x8 a0 = *(const f16x8*)(Ar0 + ko);
        f16x8 a1 = *(const f16x8*)(Ar1 + ko);
        if (kk & 1){
            a0 = bn8(a0, sc_o0, sc_o1, sh_o0, sh_o1);
            a1 = bn8(a1, sc_o0, sc_o1, sh_o0, sh_o1);
        } else {
            a0 = bn8(a0, sc_e0, sc_e1, sh_e0, sh_e1);
            a1 = bn8(a1, sc_e0, sc_e1, sh_e0, sh_e1);
        }
        #pragma unroll
        for (int n = 0; n < 8; ++n){
            f16x8 b = *(const f16x8*)(&Bh[n*16 + lr][ko + lk]);
            acc[0][n] = __builtin_amdgcn_mfma_f32_16x16x32_f16(a0, b, acc[0][n], 0, 0, 0);
            acc[1][n] = __builtin_amdgcn_mfma_f32_16x16x32_f16(a1, b, acc[1][n], 0, 0, 0);
        }
    }
    float* pp = part + (size_t)blockIdx.x*16384;
    #pragma unroll
    for (int m = 0; m < 2; ++m)
        #pragma unroll
        for (int n = 0; n < 8; ++n)
            #pragma unroll
            for (int r = 0; r < 4; ++r)
                pp[(wv*32 + m*16 + (l>>4)*4 + r)*128 + n*16 + lr] = acc[m][n][r];
}

// ---- two-stage split-K reduce ----
__global__ __launch_bounds__(256) void k_fc1_red1(const float* __restrict__ part,
                                                  float* __restrict__ part2){
    int idx = (blockIdx.x & 63)*256 + threadIdx.x;
    int seg = blockIdx.x >> 6;
    int k0 = seg*24;
    int k1 = k0 + 24 < FBLK ? k0 + 24 : FBLK;
    float s = 0.f;
    for (int kc = k0; kc < k1; ++kc) s += part[(size_t)kc*16384 + idx];
    part2[(size_t)seg*16384 + idx] = s;
}

__global__ __launch_bounds__(256) void k_fc1_red2(const float* __restrict__ part2,
                                                  const float* __restrict__ bl1,
                                                  float* __restrict__ C){
    int idx = blockIdx.x*256 + threadIdx.x;
    float s = 0.f;
    #pragma unroll
    for (int i = 0; i < 16; ++i) s += part2[(size_t)i*16384 + idx];
    C[idx] = s + bl1[idx & 127];
}

__global__ void k_fc_stats(const float* __restrict__ C, const float* __restrict__ g,
                           const float* __restrict__ be, float* scale2, float* shift2){
    int j = threadIdx.x;
    if (j < 128){
        float s = 0.f, q = 0.f;
        for (int b = 0; b < 128; ++b){ float v = C[b*128 + j]; s += v; q += v*v; }
        float mean = s / 128.f;
        float var  = q / 128.f - mean*mean;
        float sc   = g[j] / sqrtf(var + EPS);
        scale2[j] = sc;
        shift2[j] = be[j] - mean*sc;
    }
}

__global__ __launch_bounds__(256) void k_fc2(const float* __restrict__ C, const float* __restrict__ scale2,
                                             const float* __restrict__ shift2, const float* __restrict__ Wl3,
                                             const float* __restrict__ bl3, float* __restrict__ out){
    int id = blockIdx.x*256 + threadIdx.x;
    if (id < 1280){
        int b = id / 10, c = id - b*10;
        float acc = bl3[c];
        for (int j = 0; j < 128; ++j){
            float hv = fmaxf(0.f, C[b*128 + j]*scale2[j] + shift2[j]);
            acc += hv * Wl3[c*128 + j];
        }
        out[id] = acc;
    }
}

// ---------------- launch ----------------
extern "C" void kernel_launch(void* const* d_in, const int* in_sizes, int n_in,
                              void* d_out, int out_size, void* d_ws, size_t ws_size,
                              hipStream_t stream){
    const float* x   = (const float*)d_in[0];
    const int*   ei  = (const int*)  d_in[1];
    const float* ew  = (const float*)d_in[2];
    const float* W1  = (const float*)d_in[3];
    const float* b1  = (const float*)d_in[4];
    const float* W2  = (const float*)d_in[5];
    const float* b2  = (const float*)d_in[6];
    const float* W3  = (const float*)d_in[7];
    const float* b3  = (const float*)d_in[8];
    const float* g1  = (const float*)d_in[9];
    const float* be1 = (const float*)d_in[10];
    const float* g2  = (const float*)d_in[11];
    const float* be2 = (const float*)d_in[12];
    const float* g3  = (const float*)d_in[13];
    const float* be3 = (const float*)d_in[14];
    const float* Wl1 = (const float*)d_in[15];
    const float* bl1 = (const float*)d_in[16];
    const float* gl1 = (const float*)d_in[17];
    const float* bel1= (const float*)d_in[18];
    const float* Wl3 = (const float*)d_in[19];
    const float* bl3 = (const float*)d_in[20];
    const int* row = ei;
    const int* col = ei + NE;

    char* p = (char*)d_ws;
    auto alloc = [&](size_t bytes)->char*{
        char* r = p; p += (bytes + 255) & ~(size_t)255; return r;
    };
    float*  bufB     = (float*)alloc((size_t)FBLK*16384*4);     // agg scratch / FC1 partials
    float*  part2    = (float*)alloc((size_t)16*16384*4);
    __half* hpre     = (__half*)alloc((size_t)N_TOTAL*64*2);
    __half* xh       = (__half*)alloc((size_t)N_TOTAL*32*2);
    float*  dinv     = (float*)alloc(N_TOTAL*4);
    int*    cnt      = (int*)  alloc(N_TOTAL*4);
    int*    startv   = (int*)  alloc(N_TOTAL*4);
    int2*   pairsB   = (int2*) alloc((size_t)NE*8);
    int2*   pairs    = (int2*) alloc((size_t)NE*8);
    int*    blkhist  = (int*)  alloc((size_t)NBUCK*NBLKC*4);
    int*    blkoff   = (int*)  alloc((size_t)NBUCK*NBLKC*4);
    int*    btot     = (int*)  alloc(NBUCK*4);
    int*    bstart   = (int*)  alloc(NBUCK*4);
    __half* Wh1      = (__half*)alloc(2048*2);
    __half* Wh2      = (__half*)alloc(4096*2);
    __half* Wh3      = (__half*)alloc(4096*2);
    float*  gsum     = (float*)alloc(256);
    float*  gsq      = (float*)alloc(256);
    float*  scale1   = (float*)alloc(256);
    float*  shift1   = (float*)alloc(256);
    float*  scale2l  = (float*)alloc(256);
    float*  shift2l  = (float*)alloc(256);
    float*  scale3   = (float*)alloc(256);
    float*  shift3   = (float*)alloc(256);
    float*  Cfc      = (float*)alloc(65536);
    float*  scaleF   = (float*)alloc(512);
    float*  shiftF   = (float*)alloc(512);
    __half* agg32    = (__half*)bufB;
    __half* agg64    = (__half*)bufB;

    const int NB_N  = 758;     // N_TOTAL/256
    k_prepW <<<16,    256, 0, stream>>>(W1, W2, W3, Wh1, Wh2, Wh3);
    k_bktA  <<<NBLKC, 256, 0, stream>>>(col, blkhist);
    k_bktB1 <<<NBUCK, 256, 0, stream>>>(blkhist, blkoff, btot);
    k_bktB2 <<<1,     256, 0, stream>>>(btot, bstart);
    k_bktC  <<<NBLKC, 256, 0, stream>>>(row, col, ew, blkoff, bstart, pairsB);
    k_bktD1 <<<NBUCK, 256, 0, stream>>>(pairsB, bstart, btot, startv, cnt, dinv);
    k_bktD2 <<<NBUCK, 256, 0, stream>>>(pairsB, bstart, btot, startv, dinv, pairs);
    k_prep1 <<<NB_N,  256, 0, stream>>>(x, xh);

    // ---- layer 1 (aggregate-first, 32-dim fp16) ----
    k_gatherH<32,false><<<6064, 256, 0, stream>>>(xh, dinv, startv, cnt, pairs, nullptr, nullptr, agg32);
    k_gemmMF<32>       <<<3032, 256, 0, stream>>>(agg32, Wh1, b1, hpre);
    hipMemsetAsync(gsum, 0, 512, stream);
    k_bn_reduce        <<<1024, 256, 0, stream>>>(hpre, gsum, gsq);
    k_bn_final         <<<1, 64, 0, stream>>>(gsum, gsq, g1, be1, scale1, shift1);
    // ---- layer 2 (BN1+ReLU fused into gather) ----
    k_gatherH<64,true> <<<12128, 256, 0, stream>>>(hpre, dinv, startv, cnt, pairs, scale1, shift1, agg64);
    k_gemmMF<64>       <<<3032,  256, 0, stream>>>(agg64, Wh2, b2, hpre);
    hipMemsetAsync(gsum, 0, 512, stream);
    k_bn_reduce        <<<1024,  256, 0, stream>>>(hpre, gsum, gsq);
    k_bn_final         <<<1, 64, 0, stream>>>(gsum, gsq, g2, be2, scale2l, shift2l);
    // ---- layer 3 ----
    k_gatherH<64,true> <<<12128, 256, 0, stream>>>(hpre, dinv, startv, cnt, pairs, scale2l, shift2l, agg64);
    k_gemmMF<64>       <<<3032,  256, 0, stream>>>(agg64, Wh3, b3, hpre);
    hipMemsetAsync(gsum, 0, 512, stream);
    k_bn_reduce        <<<1024,  256, 0, stream>>>(hpre, gsum, gsq);
    k_bn_final         <<<1, 64, 0, stream>>>(gsum, gsq, g3, be3, scale3, shift3);

    // ---- FC head (BN3+ReLU fused into FC1 A-fragments, MFMA) ----
    k_fc1MF    <<<FBLK, 256, 0, stream>>>(hpre, Wl1, scale3, shift3, bufB);
    k_fc1_red1 <<<1024, 256, 0, stream>>>(bufB, part2);
    k_fc1_red2 <<<64,   256, 0, stream>>>(part2, bl1, Cfc);
    k_fc_stats <<<1,    128, 0, stream>>>(Cfc, gl1, bel1, scaleF, shiftF);
    k_fc2      <<<5,    256, 0, stream>>>(Cfc, scaleF, shiftF, Wl3, bl3, (float*)d_out);
}

// Round 13
// 507.025 us; speedup vs baseline: 1.0552x; 1.0313x over previous
//
#include <hip/hip_runtime.h>
#include <hip/hip_fp16.h>

#define N_TOTAL 194048
#define NE      3104768
#define HID     64
#define NNODES  1516
#define CIN     32
#define FIN     97024
#define EPS     1e-5f
#define NBUCK   758          // N_TOTAL / 256
#define NBLKC   512          // edge-chunk blocks
#define CHUNK   6064         // NE / NBLKC
#define FBLK    379          // FIN / 256
#define FCHUNK  256

using f16x8 = __attribute__((ext_vector_type(8))) _Float16;
using f32x4 = __attribute__((ext_vector_type(4))) float;

__device__ inline uint f2u(float a, float b){
    __half2 h = __floats2half2_rn(a, b);
    return *(const uint*)&h;
}
__device__ inline float2 u2f(uint u){
    __half2 h = *(const __half2*)&u;
    return __half22float2(h);
}

// ================= bucketed CSR build (no global atomics) =================
__global__ __launch_bounds__(256) void k_bktA(const int* __restrict__ col,
                                              int* __restrict__ blkhist){
    __shared__ int hist[NBUCK];
    int t = threadIdx.x;
    for (int i = t; i < NBUCK; i += 256) hist[i] = 0;
    __syncthreads();
    int base = blockIdx.x*CHUNK;
    for (int e = base + t; e < base + CHUNK; e += 256)
        atomicAdd(&hist[col[e] >> 8], 1);
    __syncthreads();
    for (int i = t; i < NBUCK; i += 256)
        blkhist[i*NBLKC + blockIdx.x] = hist[i];
}

__global__ __launch_bounds__(256) void k_bktB1(const int* __restrict__ blkhist,
                                               int* __restrict__ blkoff,
                                               int* __restrict__ btot){
    int b = blockIdx.x, t = threadIdx.x;
    const int* src = blkhist + (size_t)b*NBLKC;
    int2 v = *(const int2*)(src + t*2);
    int s0 = v.x, s1 = s0 + v.y;
    __shared__ int s[256];
    s[t] = s1; __syncthreads();
    for (int off = 1; off < 256; off <<= 1){
        int u = (t >= off) ? s[t-off] : 0;
        __syncthreads();
        s[t] += u;
        __syncthreads();
    }
    int ex = s[t] - s1;
    int* dst = blkoff + (size_t)b*NBLKC + t*2;
    dst[0] = ex; dst[1] = ex + s0;
    if (t == 255) btot[b] = ex + s1;
}

__global__ __launch_bounds__(256) void k_bktB2(const int* __restrict__ btot, int* __restrict__ bstart){
    __shared__ int s[256];
    int t = threadIdx.x;
    int i0 = t*3;
    int a = (i0   < NBUCK) ? btot[i0]   : 0;
    int b = (i0+1 < NBUCK) ? btot[i0+1] : 0;
    int c = (i0+2 < NBUCK) ? btot[i0+2] : 0;
    int tot = a+b+c;
    s[t] = tot; __syncthreads();
    for (int off = 1; off < 256; off <<= 1){
        int u = (t >= off) ? s[t-off] : 0;
        __syncthreads();
        s[t] += u;
        __syncthreads();
    }
    int ex = s[t] - tot;
    if (i0   < NBUCK) bstart[i0]   = ex;
    if (i0+1 < NBUCK) bstart[i0+1] = ex + a;
    if (i0+2 < NBUCK) bstart[i0+2] = ex + a + b;
}

// Pass C: LDS counting-sort, coalesced run write-out
__global__ __launch_bounds__(256) void k_bktC(const int* __restrict__ row, const int* __restrict__ col,
                                              const float* __restrict__ w,
                                              const int* __restrict__ blkoff,
                                              const int* __restrict__ bstart,
                                              int2* __restrict__ pairsB){
    __shared__ int2 staged[CHUNK];
    __shared__ int  lbase[NBUCK];
    __shared__ int  locoff[NBUCK];
    __shared__ int  lcur[NBUCK];
    __shared__ int  sc[256];
    int t = threadIdx.x;
    for (int i = t; i < NBUCK; i += 256){
        lbase[i] = bstart[i] + blkoff[(size_t)i*NBLKC + blockIdx.x];
        lcur[i]  = 0;
    }
    __syncthreads();
    int base = blockIdx.x*CHUNK;
    for (int e = base + t; e < base + CHUNK; e += 256)
        atomicAdd(&lcur[col[e] >> 8], 1);
    __syncthreads();
    int i0 = t*3;
    int a = (i0   < NBUCK) ? lcur[i0]   : 0;
    int b = (i0+1 < NBUCK) ? lcur[i0+1] : 0;
    int c = (i0+2 < NBUCK) ? lcur[i0+2] : 0;
    int tot = a+b+c;
    sc[t] = tot; __syncthreads();
    for (int off = 1; off < 256; off <<= 1){
        int u = (t >= off) ? sc[t-off] : 0;
        __syncthreads();
        sc[t] += u;
        __syncthreads();
    }
    int ex = sc[t] - tot;
    if (i0   < NBUCK) locoff[i0]   = ex;
    if (i0+1 < NBUCK) locoff[i0+1] = ex + a;
    if (i0+2 < NBUCK) locoff[i0+2] = ex + a + b;
    __syncthreads();
    for (int i = t; i < NBUCK; i += 256) lcur[i] = locoff[i];
    __syncthreads();
    for (int e = base + t; e < base + CHUNK; e += 256){
        int cc = col[e];
        int bb = cc >> 8;
        int rk = atomicAdd(&lcur[bb], 1);
        staged[rk] = make_int2(row[e] | ((cc & 255) << 18), __float_as_int(w[e]));
    }
    __syncthreads();
    for (int j = t; j < CHUNK; j += 256){
        int lo = 0, hi = NBUCK - 1;
        while (lo < hi){
            int mid = (lo + hi + 1) >> 1;
            if (locoff[mid] <= j) lo = mid; else hi = mid - 1;
        }
        pairsB[lbase[lo] + (j - locoff[lo])] = staged[j];
    }
}

// Pass D1: per-bucket node stats -> startv, cnt, dinv
__global__ __launch_bounds__(256) void k_bktD1(const int2* __restrict__ pairsB,
                                               const int* __restrict__ bstart,
                                               const int* __restrict__ btot,
                                               int* __restrict__ startv, int* __restrict__ cnt,
                                               float* __restrict__ dinv){
    __shared__ int   nh[256];
    __shared__ float ws[256];
    __shared__ int   sc[256];
    int b = blockIdx.x, t = threadIdx.x;
    nh[t] = 0; ws[t] = 0.f;
    __syncthreads();
    int s0 = bstart[b];
    int n  = btot[b];
    for (int e = s0 + t; e < s0 + n; e += 256){
        int2 p = pairsB[e];
        int lo = (p.x >> 18) & 255;
        atomicAdd(&nh[lo], 1);
        atomicAdd(&ws[lo], __int_as_float(p.y));
    }
    __syncthreads();
    int my = nh[t];
    sc[t] = my; __syncthreads();
    for (int off = 1; off < 256; off <<= 1){
        int u = (t >= off) ? sc[t-off] : 0;
        __syncthreads();
        sc[t] += u;
        __syncthreads();
    }
    int ex = sc[t] - my;
    int node = b*256 + t;
    startv[node] = s0 + ex;
    cnt[node]    = my;
    dinv[node]   = rsqrtf(1.0f + ws[t]);
}

// Pass D2: scatter to node-grouped pairs with norm fold (w *= dinv[src])
__global__ __launch_bounds__(256) void k_bktD2(const int2* __restrict__ pairsB,
                                               const int* __restrict__ bstart,
                                               const int* __restrict__ btot,
                                               const int* __restrict__ startv,
                                               const float* __restrict__ dinv,
                                               int2* __restrict__ pairs){
    __shared__ int sbase[256];
    __shared__ int rank[256];
    int b = blockIdx.x, t = threadIdx.x;
    sbase[t] = startv[b*256 + t];
    rank[t]  = 0;
    __syncthreads();
    int s0 = bstart[b];
    int n  = btot[b];
    for (int e = s0 + t; e < s0 + n; e += 256){
        int2 p = pairsB[e];
        int lo  = (p.x >> 18) & 255;
        int src = p.x & 0x3FFFF;
        float nw = __int_as_float(p.y) * dinv[src];
        int rk = atomicAdd(&rank[lo], 1);
        pairs[sbase[lo] + rk] = make_int2(src, __float_as_int(nw));
    }
}

// ---------------- fused prep: x transpose + W fp16 conversion + stats zero ----------------
__global__ __launch_bounds__(256) void k_prep(const float* __restrict__ x, __half* __restrict__ xh,
                                              const float* __restrict__ W1, const float* __restrict__ W2,
                                              const float* __restrict__ W3,
                                              __half* __restrict__ Wh1, __half* __restrict__ Wh2,
                                              __half* __restrict__ Wh3, float* __restrict__ stats){
    int t = threadIdx.x;
    int idx = blockIdx.x*256 + t;
    if (idx < 2048) Wh1[idx] = __float2half(W1[idx]);
    if (idx < 4096){ Wh2[idx] = __float2half(W2[idx]); Wh3[idx] = __float2half(W3[idx]); }
    if (idx < 384) stats[idx] = 0.f;
    if (idx >= N_TOTAL) return;
    int b = idx / NNODES, nn = idx - b*NNODES;
    const float* xp = x + (size_t)b*CIN*NNODES + nn;
    uint u[16];
    #pragma unroll
    for (int c2 = 0; c2 < 16; ++c2){
        float a0 = xp[(size_t)(2*c2)*NNODES];
        float a1 = xp[(size_t)(2*c2+1)*NNODES];
        u[c2] = f2u(a0, a1);
    }
    uint4* dst = (uint4*)(xh + (size_t)idx*CIN);
    dst[0] = make_uint4(u[0], u[1], u[2],  u[3]);
    dst[1] = make_uint4(u[4], u[5], u[6],  u[7]);
    dst[2] = make_uint4(u[8], u[9], u[10], u[11]);
    dst[3] = make_uint4(u[12],u[13],u[14], u[15]);
}

// ---------------- gather helpers ----------------
template<bool BN>
__device__ inline void acc4(float n, uint2 u, const float4& sc, const float4& sh,
                            float& a0, float& a1, float& a2, float& a3){
    float2 lo = u2f(u.x), hi = u2f(u.y);
    float v0, v1, v2, v3;
    if (BN){
        v0 = fmaxf(0.f, lo.x*sc.x + sh.x); v1 = fmaxf(0.f, lo.y*sc.y + sh.y);
        v2 = fmaxf(0.f, hi.x*sc.z + sh.z); v3 = fmaxf(0.f, hi.y*sc.w + sh.w);
    } else { v0 = lo.x; v1 = lo.y; v2 = hi.x; v3 = hi.y; }
    a0 += n*v0; a1 += n*v1; a2 += n*v2; a3 += n*v3;
}

// ---------------- FUSED gather + GEMM: out[n][64] = (A_hat . f(h)) @ Wh^T + bias ----------------
// BN scale/shift computed in-prologue from gsum/gsq/g/be (bn_final folded in).
// Gather: F/4 lanes per node, 8-deep MLP. GEMM: verified 16x16x32 MFMA pattern.
template<int F, bool BN>
__global__ __launch_bounds__(256) void k_gg(const __half* __restrict__ h,
                                            const float* __restrict__ dinv,
                                            const int* __restrict__ startv,
                                            const int* __restrict__ cnt,
                                            const int2* __restrict__ pairs,
                                            const float* __restrict__ gsum,
                                            const float* __restrict__ gsq,
                                            const float* __restrict__ g,
                                            const float* __restrict__ be,
                                            const __half* __restrict__ Wh,
                                            const float* __restrict__ bias,
                                            __half* __restrict__ out){
    constexpr int LPN   = F/4;
    constexpr int NODES = 256/LPN;   // 16 (F=64) or 32 (F=32)
    __shared__ float s_sc[64], s_sh[64];
    __shared__ __align__(16) __half sA[NODES][F + 8];
    __shared__ __align__(16) __half sO[NODES][72];
    int t = threadIdx.x;
    if (BN){
        if (t < 64){
            float mean = gsum[t] * (1.0f/(float)N_TOTAL);
            float var  = gsq[t]  * (1.0f/(float)N_TOTAL) - mean*mean;
            float scv  = g[t] / sqrtf(var + EPS);
            s_sc[t] = scv;
            s_sh[t] = be[t] - mean*scv;
        }
        __syncthreads();
    }
    int nl   = t / LPN;
    int q    = (t % LPN)*4;
    int node = blockIdx.x*NODES + nl;
    const __half* hq = h + q;
    float4 sc = make_float4(0,0,0,0), sh = make_float4(0,0,0,0);
    if (BN){ sc = *(const float4*)(s_sc + q); sh = *(const float4*)(s_sh + q); }
    float a0 = 0.f, a1 = 0.f, a2 = 0.f, a3 = 0.f;

    int s = startv[node];
    int e = s + cnt[node];
    for (; s + 8 <= e; s += 8){
        int2 p0 = pairs[s],   p1 = pairs[s+1], p2 = pairs[s+2], p3 = pairs[s+3];
        int2 p4 = pairs[s+4], p5 = pairs[s+5], p6 = pairs[s+6], p7 = pairs[s+7];
        uint2 u0 = *(const uint2*)(hq + (size_t)p0.x*F);
        uint2 u1 = *(const uint2*)(hq + (size_t)p1.x*F);
        uint2 u2v= *(const uint2*)(hq + (size_t)p2.x*F);
        uint2 u3 = *(const uint2*)(hq + (size_t)p3.x*F);
        uint2 u4 = *(const uint2*)(hq + (size_t)p4.x*F);
        uint2 u5 = *(const uint2*)(hq + (size_t)p5.x*F);
        uint2 u6 = *(const uint2*)(hq + (size_t)p6.x*F);
        uint2 u7 = *(const uint2*)(hq + (size_t)p7.x*F);
        acc4<BN>(__int_as_float(p0.y), u0,  sc, sh, a0, a1, a2, a3);
        acc4<BN>(__int_as_float(p1.y), u1,  sc, sh, a0, a1, a2, a3);
        acc4<BN>(__int_as_float(p2.y), u2v, sc, sh, a0, a1, a2, a3);
        acc4<BN>(__int_as_float(p3.y), u3,  sc, sh, a0, a1, a2, a3);
        acc4<BN>(__int_as_float(p4.y), u4,  sc, sh, a0, a1, a2, a3);
        acc4<BN>(__int_as_float(p5.y), u5,  sc, sh, a0, a1, a2, a3);
        acc4<BN>(__int_as_float(p6.y), u6,  sc, sh, a0, a1, a2, a3);
        acc4<BN>(__int_as_float(p7.y), u7,  sc, sh, a0, a1, a2, a3);
    }
    for (; s + 4 <= e; s += 4){
        int2 p0 = pairs[s], p1 = pairs[s+1], p2 = pairs[s+2], p3 = pairs[s+3];
        uint2 u0 = *(const uint2*)(hq + (size_t)p0.x*F);
        uint2 u1 = *(const uint2*)(hq + (size_t)p1.x*F);
        uint2 u2v= *(const uint2*)(hq + (size_t)p2.x*F);
        uint2 u3 = *(const uint2*)(hq + (size_t)p3.x*F);
        acc4<BN>(__int_as_float(p0.y), u0,  sc, sh, a0, a1, a2, a3);
        acc4<BN>(__int_as_float(p1.y), u1,  sc, sh, a0, a1, a2, a3);
        acc4<BN>(__int_as_float(p2.y), u2v, sc, sh, a0, a1, a2, a3);
        acc4<BN>(__int_as_float(p3.y), u3,  sc, sh, a0, a1, a2, a3);
    }
    for (; s < e; ++s){
        int2 p0 = pairs[s];
        uint2 u0 = *(const uint2*)(hq + (size_t)p0.x*F);
        acc4<BN>(__int_as_float(p0.y), u0, sc, sh, a0, a1, a2, a3);
    }
    float di = dinv[node];
    a0 *= di; a1 *= di; a2 *= di; a3 *= di;
    uint2 us = *(const uint2*)(hq + (size_t)node*F);
    acc4<BN>(di*di, us, sc, sh, a0, a1, a2, a3);   // self-loop
    *(uint2*)(&sA[nl][q]) = make_uint2(f2u(a0,a1), f2u(a2,a3));
    __syncthreads();

    // ---- MFMA GEMM on staged agg (pattern identical to verified k_gemmMF) ----
    int wv = t >> 6, l = t & 63;
    int lr = l & 15, lk = (l >> 4)*8;
    if (F == 64){
        f16x8 af0 = *(const f16x8*)(&sA[lr][lk]);
        f16x8 af1 = *(const f16x8*)(&sA[lr][32 + lk]);
        f16x8 bf0 = *(const f16x8*)(Wh + (size_t)(wv*16 + lr)*64 + lk);
        f16x8 bf1 = *(const f16x8*)(Wh + (size_t)(wv*16 + lr)*64 + 32 + lk);
        f32x4 acc = (f32x4){0.f, 0.f, 0.f, 0.f};
        acc = __builtin_amdgcn_mfma_f32_16x16x32_f16(af0, bf0, acc, 0, 0, 0);
        acc = __builtin_amdgcn_mfma_f32_16x16x32_f16(af1, bf1, acc, 0, 0, 0);
        float bb = bias[wv*16 + lr];
        #pragma unroll
        for (int r = 0; r < 4; ++r)
            sO[(l>>4)*4 + r][wv*16 + lr] = __float2half(acc[r] + bb);
    } else {
        f16x8 bf = *(const f16x8*)(Wh + (size_t)(wv*16 + lr)*32 + lk);
        float bb = bias[wv*16 + lr];
        #pragma unroll
        for (int rt = 0; rt < 2; ++rt){
            f16x8 af = *(const f16x8*)(&sA[rt*16 + lr][lk]);
            f32x4 acc = (f32x4){0.f, 0.f, 0.f, 0.f};
            acc = __builtin_amdgcn_mfma_f32_16x16x32_f16(af, bf, acc, 0, 0, 0);
            #pragma unroll
            for (int r = 0; r < 4; ++r)
                sO[rt*16 + (l>>4)*4 + r][wv*16 + lr] = __float2half(acc[r] + bb);
        }
    }
    __syncthreads();
    int base = blockIdx.x*NODES;
    if (F == 64){
        int rr = t >> 4, cb = (t & 15)*4;
        *(uint2*)(out + (size_t)(base + rr)*64 + cb) = *(const uint2*)(&sO[rr][cb]);
    } else {
        int rr = t >> 3, cb = (t & 7)*8;
        *(uint4*)(out + (size_t)(base + rr)*64 + cb) = *(const uint4*)(&sO[rr][cb]);
    }
}

// ---------------- BN stats over node axis (fp16 input) ----------------
__global__ __launch_bounds__(256) void k_bn_reduce(const __half* __restrict__ x, float* gsum, float* gsq){
    int t = threadIdx.x;
    int f = t & 63, g4 = t >> 6;
    float s = 0.f, q = 0.f;
    for (int i = blockIdx.x*4 + g4; i < N_TOTAL; i += gridDim.x*4){
        float v = __half2float(x[(size_t)i*64 + f]);
        s += v; q += v*v;
    }
    __shared__ float sh[2][4][64];
    sh[0][g4][f] = s; sh[1][g4][f] = q;
    __syncthreads();
    if (t < 64){
        float ss = sh[0][0][t] + sh[0][1][t] + sh[0][2][t] + sh[0][3][t];
        float qq = sh[1][0][t] + sh[1][1][t] + sh[1][2][t] + sh[1][3][t];
        atomicAdd(&gsum[t], ss);
        atomicAdd(&gsq[t],  qq);
    }
}

// ---------------- FC1 on MFMA (bn_final folded into prologue) ----------------
__device__ inline f16x8 bn8(f16x8 v, const float4& s0, const float4& s1,
                            const float4& h0, const float4& h1){
    uint4 u = *(uint4*)&v;
    float2 p0 = u2f(u.x), p1 = u2f(u.y), p2 = u2f(u.z), p3 = u2f(u.w);
    float r0 = fmaxf(0.f, p0.x*s0.x + h0.x);
    float r1 = fmaxf(0.f, p0.y*s0.y + h0.y);
    float r2 = fmaxf(0.f, p1.x*s0.z + h0.z);
    float r3 = fmaxf(0.f, p1.y*s0.w + h0.w);
    float r4 = fmaxf(0.f, p2.x*s1.x + h1.x);
    float r5 = fmaxf(0.f, p2.y*s1.y + h1.y);
    float r6 = fmaxf(0.f, p3.x*s1.z + h1.z);
    float r7 = fmaxf(0.f, p3.y*s1.w + h1.w);
    uint4 o = make_uint4(f2u(r0,r1), f2u(r2,r3), f2u(r4,r5), f2u(r6,r7));
    return *(f16x8*)&o;
}

__global__ __launch_bounds__(256) void k_fc1MF(const __half* __restrict__ A,
                                               const float* __restrict__ Wl1,
                                               const float* __restrict__ gsum,
                                               const float* __restrict__ gsq,
                                               const float* __restrict__ g,
                                               const float* __restrict__ be,
                                               float* __restrict__ part){
    __shared__ __align__(16) __half Bh[128][264];
    __shared__ float s_sc[64], s_sh[64];
    int t = threadIdx.x;
    if (t < 64){
        float mean = gsum[t] * (1.0f/(float)N_TOTAL);
        float var  = gsq[t]  * (1.0f/(float)N_TOTAL) - mean*mean;
        float scv  = g[t] / sqrtf(var + EPS);
        s_sc[t] = scv;
        s_sh[t] = be[t] - mean*scv;
    }
    int kbase = blockIdx.x * FCHUNK;
    #pragma unroll
    for (int i = 0; i < 32; ++i){
        int flat = i*1024 + t*4;
        int r = flat >> 8, k = flat & 255;
        float4 w = *(const float4*)(Wl1 + (size_t)r*FIN + kbase + k);
        *(uint2*)(&Bh[r][k]) = make_uint2(f2u(w.x, w.y), f2u(w.z, w.w));
    }

    int wv = t >> 6, l = t & 63;
    int lr = l & 15, lk = (l >> 4)*8;
    const __half* Ar0 = A + (size_t)(wv*32 + lr)*FIN + kbase + lk;
    const __half* Ar1 = A + (size_t)(wv*32 + 16 + lr)*FIN + kbase + lk;

    f32x4 acc[2][8];
    #pragma unroll
    for (int m = 0; m < 2; ++m)
        #pragma unroll
        for (int n = 0; n < 8; ++n) acc[m][n] = (f32x4){0.f, 0.f, 0.f, 0.f};

    __syncthreads();
    float4 sc_e0 = *(const float4*)(s_sc + lk),      sc_e1 = *(const float4*)(s_sc + lk + 4);
    float4 sc_o0 = *(const float4*)(s_sc + 32 + lk), sc_o1 = *(const float4*)(s_sc + 36 + lk);
    float4 sh_e0 = *(const float4*)(s_sh + lk),      sh_e1 = *(const float4*)(s_sh + lk + 4);
    float4 sh_o0 = *(const float4*)(s_sh + 32 + lk), sh_o1 = *(const float4*)(s_sh + 36 + lk);

    #pragma unroll
    for (int kk = 0; kk < 8; ++kk){
        int ko = kk*32;
        f16x8 a0 = *(const f16x8*)(Ar0 + ko);
        f16x8 a1 = *(const f16x8*)(Ar1 + ko);
        if (kk & 1){
            a0 = bn8(a0, sc_o0, sc_o1, sh_o0, sh_o1);
            a1 = bn8(a1, sc_o0, sc_o1, sh_o0, sh_o1);
        } else {
            a0 = bn8(a0, sc_e0, sc_e1, sh_e0, sh_e1);
            a1 = bn8(a1, sc_e0, sc_e1, sh_e0, sh_e1);
        }
        #pragma unroll
        for (int n = 0; n < 8; ++n){
            f16x8 b = *(const f16x8*)(&Bh[n*16 + lr][ko + lk]);
            acc[0][n] = __builtin_amdgcn_mfma_f32_16x16x32_f16(a0, b, acc[0][n], 0, 0, 0);
            acc[1][n] = __builtin_amdgcn_mfma_f32_16x16x32_f16(a1, b, acc[1][n], 0, 0, 0);
        }
    }
    float* pp = part + (size_t)blockIdx.x*16384;
    #pragma unroll
    for (int m = 0; m < 2; ++m)
        #pragma unroll
        for (int n = 0; n < 8; ++n)
            #pragma unroll
            for (int r = 0; r < 4; ++r)
                pp[(wv*32 + m*16 + (l>>4)*4 + r)*128 + n*16 + lr] = acc[m][n][r];
}

// ---- two-stage split-K reduce ----
__global__ __launch_bounds__(256) void k_fc1_red1(const float* __restrict__ part,
                                                  float* __restrict__ part2){
    int idx = (blockIdx.x & 63)*256 + threadIdx.x;
    int seg = blockIdx.x >> 6;
    int k0 = seg*24;
    int k1 = k0 + 24 < FBLK ? k0 + 24 : FBLK;
    float s = 0.f;
    for (int kc = k0; kc < k1; ++kc) s += part[(size_t)kc*16384 + idx];
    part2[(size_t)seg*16384 + idx] = s;
}

__global__ __launch_bounds__(256) void k_fc1_red2(const float* __restrict__ part2,
                                                  const float* __restrict__ bl1,
                                                  float* __restrict__ C){
    int idx = blockIdx.x*256 + threadIdx.x;
    float s = 0.f;
    #pragma unroll
    for (int i = 0; i < 16; ++i) s += part2[(size_t)i*16384 + idx];
    C[idx] = s + bl1[idx & 127];
}

// ---------------- fused BN stats + FC2 (single block) ----------------
__global__ __launch_bounds__(256) void k_fcTail(const float* __restrict__ C,
                                                const float* __restrict__ gl1,
                                                const float* __restrict__ bel1,
                                                const float* __restrict__ Wl3,
                                                const float* __restrict__ bl3,
                                                float* __restrict__ out){
    __shared__ float ssc[128], ssh[128];
    int t = threadIdx.x;
    if (t < 128){
        float s = 0.f, q = 0.f;
        for (int b = 0; b < 128; ++b){ float v = C[b*128 + t]; s += v; q += v*v; }
        float mean = s / 128.f;
        float var  = q / 128.f - mean*mean;
        float scv  = gl1[t] / sqrtf(var + EPS);
        ssc[t] = scv;
        ssh[t] = bel1[t] - mean*scv;
    }
    __syncthreads();
    for (int id = t; id < 1280; id += 256){
        int b = id / 10, c = id - b*10;
        float acc = bl3[c];
        for (int j = 0; j < 128; ++j){
            float hv = fmaxf(0.f, C[b*128 + j]*ssc[j] + ssh[j]);
            acc += hv * Wl3[c*128 + j];
        }
        out[id] = acc;
    }
}

// ---------------- launch ----------------
extern "C" void kernel_launch(void* const* d_in, const int* in_sizes, int n_in,
                              void* d_out, int out_size, void* d_ws, size_t ws_size,
                              hipStream_t stream){
    const float* x   = (const float*)d_in[0];
    const int*   ei  = (const int*)  d_in[1];
    const float* ew  = (const float*)d_in[2];
    const float* W1  = (const float*)d_in[3];
    const float* b1  = (const float*)d_in[4];
    const float* W2  = (const float*)d_in[5];
    const float* b2  = (const float*)d_in[6];
    const float* W3  = (const float*)d_in[7];
    const float* b3  = (const float*)d_in[8];
    const float* g1  = (const float*)d_in[9];
    const float* be1 = (const float*)d_in[10];
    const float* g2  = (const float*)d_in[11];
    const float* be2 = (const float*)d_in[12];
    const float* g3  = (const float*)d_in[13];
    const float* be3 = (const float*)d_in[14];
    const float* Wl1 = (const float*)d_in[15];
    const float* bl1 = (const float*)d_in[16];
    const float* gl1 = (const float*)d_in[17];
    const float* bel1= (const float*)d_in[18];
    const float* Wl3 = (const float*)d_in[19];
    const float* bl3 = (const float*)d_in[20];
    const int* row = ei;
    const int* col = ei + NE;

    char* p = (char*)d_ws;
    auto alloc = [&](size_t bytes)->char*{
        char* r = p; p += (bytes + 255) & ~(size_t)255; return r;
    };
    int2*   pairsB   = (int2*) alloc((size_t)NE*8);             // aliased: FC1 partials (same size)
    float*  bufB     = (float*)pairsB;                          // FBLK*16384*4 == NE*8
    float*  part2    = (float*)alloc((size_t)16*16384*4);
    __half* hA       = (__half*)alloc((size_t)N_TOTAL*64*2);
    __half* hB       = (__half*)alloc((size_t)N_TOTAL*64*2);
    __half* xh       = (__half*)alloc((size_t)N_TOTAL*32*2);
    float*  dinv     = (float*)alloc(N_TOTAL*4);
    int*    cnt      = (int*)  alloc(N_TOTAL*4);
    int*    startv   = (int*)  alloc(N_TOTAL*4);
    int2*   pairs    = (int2*) alloc((size_t)NE*8);
    int*    blkhist  = (int*)  alloc((size_t)NBUCK*NBLKC*4);
    int*    blkoff   = (int*)  alloc((size_t)NBUCK*NBLKC*4);
    int*    btot     = (int*)  alloc(NBUCK*4);
    int*    bstart   = (int*)  alloc(NBUCK*4);
    __half* Wh1      = (__half*)alloc(2048*2);
    __half* Wh2      = (__half*)alloc(4096*2);
    __half* Wh3      = (__half*)alloc(4096*2);
    float*  stats    = (float*)alloc(1536);    // 6x64: gsum1,gsq1,gsum2,gsq2,gsum3,gsq3
    float*  Cfc      = (float*)alloc(65536);
    float* gsum1 = stats,        *gsq1 = stats + 64;
    float* gsum2 = stats + 128,  *gsq2 = stats + 192;
    float* gsum3 = stats + 256,  *gsq3 = stats + 320;

    k_prep  <<<758,   256, 0, stream>>>(x, xh, W1, W2, W3, Wh1, Wh2, Wh3, stats);
    k_bktA  <<<NBLKC, 256, 0, stream>>>(col, blkhist);
    k_bktB1 <<<NBUCK, 256, 0, stream>>>(blkhist, blkoff, btot);
    k_bktB2 <<<1,     256, 0, stream>>>(btot, bstart);
    k_bktC  <<<NBLKC, 256, 0, stream>>>(row, col, ew, blkoff, bstart, pairsB);
    k_bktD1 <<<NBUCK, 256, 0, stream>>>(pairsB, bstart, btot, startv, cnt, dinv);
    k_bktD2 <<<NBUCK, 256, 0, stream>>>(pairsB, bstart, btot, startv, dinv, pairs);

    // ---- layer 1: fused gather(32)+GEMM -> hA ----
    k_gg<32,false><<<6064,  256, 0, stream>>>(xh, dinv, startv, cnt, pairs,
                                              nullptr, nullptr, nullptr, nullptr, Wh1, b1, hA);
    k_bn_reduce   <<<1024,  256, 0, stream>>>(hA, gsum1, gsq1);
    // ---- layer 2: fused BN1+gather(64)+GEMM -> hB ----
    k_gg<64,true> <<<12128, 256, 0, stream>>>(hA, dinv, startv, cnt, pairs,
                                              gsum1, gsq1, g1, be1, Wh2, b2, hB);
    k_bn_reduce   <<<1024,  256, 0, stream>>>(hB, gsum2, gsq2);
    // ---- layer 3: fused BN2+gather(64)+GEMM -> hA ----
    k_gg<64,true> <<<12128, 256, 0, stream>>>(hB, dinv, startv, cnt, pairs,
                                              gsum2, gsq2, g2, be2, Wh3, b3, hA);
    k_bn_reduce   <<<1024,  256, 0, stream>>>(hA, gsum3, gsq3);

    // ---- FC head (BN3 folded into FC1 prologue; pairsB memory reused as partials) ----
    k_fc1MF    <<<FBLK, 256, 0, stream>>>(hA, Wl1, gsum3, gsq3, g3, be3, bufB);
    k_fc1_red1 <<<1024, 256, 0, stream>>>(bufB, part2);
    k_fc1_red2 <<<64,   256, 0, stream>>>(part2, bl1, Cfc);
    k_fcTail   <<<1,    256, 0, stream>>>(Cfc, gl1, bel1, Wl3, bl3, (float*)d_out);
}

// Round 15
// 499.415 us; speedup vs baseline: 1.0713x; 1.0152x over previous
//
#include <hip/hip_runtime.h>
#include <hip/hip_fp16.h>

#define N_TOTAL 194048
#define NE      3104768
#define HID     64
#define NNODES  1516
#define CIN     32
#define FIN     97024
#define EPS     1e-5f
#define NBUCK   758          // N_TOTAL / 256
#define NBLKC   512          // edge-chunk blocks
#define CHUNK   6064         // NE / NBLKC
#define CAP     5120         // padded edges per bucket (mean 4096 + 16 sigma)
#define FBLK    379          // FIN / 256
#define FCHUNK  256

using f16x8 = __attribute__((ext_vector_type(8))) _Float16;
using f32x4 = __attribute__((ext_vector_type(4))) float;

__device__ inline uint f2u(float a, float b){
    __half2 h = __floats2half2_rn(a, b);
    return *(const uint*)&h;
}
__device__ inline float2 u2f(uint u){
    __half2 h = *(const __half2*)&u;
    return __half22float2(h);
}

// ---------------- fused prep: x transpose + W fp16 + stats/cursor zero ----------------
__global__ __launch_bounds__(256) void k_prep(const float* __restrict__ x, __half* __restrict__ xh,
                                              const float* __restrict__ W1, const float* __restrict__ W2,
                                              const float* __restrict__ W3,
                                              __half* __restrict__ Wh1, __half* __restrict__ Wh2,
                                              __half* __restrict__ Wh3, float* __restrict__ stats,
                                              int* __restrict__ cursor){
    int t = threadIdx.x;
    int idx = blockIdx.x*256 + t;
    if (idx < 2048) Wh1[idx] = __float2half(W1[idx]);
    if (idx < 4096){ Wh2[idx] = __float2half(W2[idx]); Wh3[idx] = __float2half(W3[idx]); }
    if (idx < 384) stats[idx] = 0.f;
    if (idx < NBUCK) cursor[idx] = 0;
    if (idx >= N_TOTAL) return;
    int b = idx / NNODES, nn = idx - b*NNODES;
    const float* xp = x + (size_t)b*CIN*NNODES + nn;
    uint u[16];
    #pragma unroll
    for (int c2 = 0; c2 < 16; ++c2){
        float a0 = xp[(size_t)(2*c2)*NNODES];
        float a1 = xp[(size_t)(2*c2+1)*NNODES];
        u[c2] = f2u(a0, a1);
    }
    uint4* dst = (uint4*)(xh + (size_t)idx*CIN);
    dst[0] = make_uint4(u[0], u[1], u[2],  u[3]);
    dst[1] = make_uint4(u[4], u[5], u[6],  u[7]);
    dst[2] = make_uint4(u[8], u[9], u[10], u[11]);
    dst[3] = make_uint4(u[12],u[13],u[14], u[15]);
}

// ================= single-pass bucketed scatter =================
// LDS counting-sort of the block's chunk (proven round-12 pattern), then one
// atomic region-reservation per (bucket,block) run, then coalesced run write-out
// into the bucket's fixed padded region [b*CAP, (b+1)*CAP).
__global__ __launch_bounds__(256) void k_bktC2(const int* __restrict__ row, const int* __restrict__ col,
                                               const float* __restrict__ w,
                                               int* __restrict__ cursor,
                                               int2* __restrict__ pairsB){
    __shared__ int2 staged[CHUNK];
    __shared__ int  gbase[NBUCK];
    __shared__ int  locoff[NBUCK];
    __shared__ int  lcur[NBUCK];
    __shared__ int  sc[256];
    int t = threadIdx.x;
    for (int i = t; i < NBUCK; i += 256) lcur[i] = 0;
    __syncthreads();
    int base = blockIdx.x*CHUNK;
    // local histogram
    for (int e = base + t; e < base + CHUNK; e += 256)
        atomicAdd(&lcur[col[e] >> 8], 1);
    __syncthreads();
    // exclusive scan lcur -> locoff
    int i0 = t*3;
    int a = (i0   < NBUCK) ? lcur[i0]   : 0;
    int b = (i0+1 < NBUCK) ? lcur[i0+1] : 0;
    int c = (i0+2 < NBUCK) ? lcur[i0+2] : 0;
    int tot = a+b+c;
    sc[t] = tot; __syncthreads();
    for (int off = 1; off < 256; off <<= 1){
        int u = (t >= off) ? sc[t-off] : 0;
        __syncthreads();
        sc[t] += u;
        __syncthreads();
    }
    int ex = sc[t] - tot;
    if (i0   < NBUCK) locoff[i0]   = ex;
    if (i0+1 < NBUCK) locoff[i0+1] = ex + a;
    if (i0+2 < NBUCK) locoff[i0+2] = ex + a + b;
    __syncthreads();
    for (int i = t; i < NBUCK; i += 256) lcur[i] = locoff[i];
    __syncthreads();
    // rank-place into staged (bucket-sorted)
    for (int e = base + t; e < base + CHUNK; e += 256){
        int cc = col[e];
        int bb = cc >> 8;
        int rk = atomicAdd(&lcur[bb], 1);
        staged[rk] = make_int2(row[e] | ((cc & 255) << 18), __float_as_int(w[e]));
    }
    __syncthreads();
    // reserve each bucket's run in its padded global region
    for (int i = t; i < NBUCK; i += 256){
        int L = ((i == NBUCK-1) ? CHUNK : locoff[i+1]) - locoff[i];
        if (L > 0){
            int old = atomicAdd(&cursor[i], L);
            gbase[i] = (old + L <= CAP) ? (i*CAP + old) : -1;   // overflow guard (never fires)
        } else gbase[i] = -1;
    }
    __syncthreads();
    // coalesced write-out: dest = gbase[b] + (j - locoff[b]); b via binary search
    for (int j = t; j < CHUNK; j += 256){
        int lo = 0, hi = NBUCK - 1;
        while (lo < hi){
            int mid = (lo + hi + 1) >> 1;
            if (locoff[mid] <= j) lo = mid; else hi = mid - 1;
        }
        int gb = gbase[lo];
        if (gb >= 0) pairsB[gb + (j - locoff[lo])] = staged[j];
    }
}

// Pass D1: per-bucket node stats -> startv, cnt, dinv (bucket region = [b*CAP, b*CAP+cursor[b]))
__global__ __launch_bounds__(256) void k_bktD1(const int2* __restrict__ pairsB,
                                               const int* __restrict__ cursor,
                                               int* __restrict__ startv, int* __restrict__ cnt,
                                               float* __restrict__ dinv){
    __shared__ int   nh[256];
    __shared__ float ws[256];
    __shared__ int   sc[256];
    int b = blockIdx.x, t = threadIdx.x;
    nh[t] = 0; ws[t] = 0.f;
    __syncthreads();
    int s0 = b*CAP;
    int n  = cursor[b];
    for (int e = s0 + t; e < s0 + n; e += 256){
        int2 p = pairsB[e];
        int lo = (p.x >> 18) & 255;
        atomicAdd(&nh[lo], 1);
        atomicAdd(&ws[lo], __int_as_float(p.y));
    }
    __syncthreads();
    int my = nh[t];
    sc[t] = my; __syncthreads();
    for (int off = 1; off < 256; off <<= 1){
        int u = (t >= off) ? sc[t-off] : 0;
        __syncthreads();
        sc[t] += u;
        __syncthreads();
    }
    int ex = sc[t] - my;
    int node = b*256 + t;
    startv[node] = s0 + ex;
    cnt[node]    = my;
    dinv[node]   = rsqrtf(1.0f + ws[t]);
}

// Pass D2: scatter to node-grouped pairs with norm fold (w *= dinv[src])
__global__ __launch_bounds__(256) void k_bktD2(const int2* __restrict__ pairsB,
                                               const int* __restrict__ cursor,
                                               const int* __restrict__ startv,
                                               const float* __restrict__ dinv,
                                               int2* __restrict__ pairs){
    __shared__ int sbase[256];
    __shared__ int rank[256];
    int b = blockIdx.x, t = threadIdx.x;
    sbase[t] = startv[b*256 + t];
    rank[t]  = 0;
    __syncthreads();
    int s0 = b*CAP;
    int n  = cursor[b];
    for (int e = s0 + t; e < s0 + n; e += 256){
        int2 p = pairsB[e];
        int lo  = (p.x >> 18) & 255;
        int src = p.x & 0x3FFFF;
        float nw = __int_as_float(p.y) * dinv[src];
        int rk = atomicAdd(&rank[lo], 1);
        pairs[sbase[lo] + rk] = make_int2(src, __float_as_int(nw));
    }
}

// ---------------- gather helpers ----------------
template<bool BN>
__device__ inline void acc4(float n, uint2 u, const float4& sc, const float4& sh,
                            float& a0, float& a1, float& a2, float& a3){
    float2 lo = u2f(u.x), hi = u2f(u.y);
    float v0, v1, v2, v3;
    if (BN){
        v0 = fmaxf(0.f, lo.x*sc.x + sh.x); v1 = fmaxf(0.f, lo.y*sc.y + sh.y);
        v2 = fmaxf(0.f, hi.x*sc.z + sh.z); v3 = fmaxf(0.f, hi.y*sc.w + sh.w);
    } else { v0 = lo.x; v1 = lo.y; v2 = hi.x; v3 = hi.y; }
    a0 += n*v0; a1 += n*v1; a2 += n*v2; a3 += n*v3;
}

// ---------------- FUSED gather + GEMM ----------------
template<int F, bool BN>
__global__ __launch_bounds__(256) void k_gg(const __half* __restrict__ h,
                                            const float* __restrict__ dinv,
                                            const int* __restrict__ startv,
                                            const int* __restrict__ cnt,
                                            const int2* __restrict__ pairs,
                                            const float* __restrict__ gsum,
                                            const float* __restrict__ gsq,
                                            const float* __restrict__ g,
                                            const float* __restrict__ be,
                                            const __half* __restrict__ Wh,
                                            const float* __restrict__ bias,
                                            __half* __restrict__ out){
    constexpr int LPN   = F/4;
    constexpr int NODES = 256/LPN;
    __shared__ float s_sc[64], s_sh[64];
    __shared__ __align__(16) __half sA[NODES][F + 8];
    __shared__ __align__(16) __half sO[NODES][72];
    int t = threadIdx.x;
    if (BN){
        if (t < 64){
            float mean = gsum[t] * (1.0f/(float)N_TOTAL);
            float var  = gsq[t]  * (1.0f/(float)N_TOTAL) - mean*mean;
            float scv  = g[t] / sqrtf(var + EPS);
            s_sc[t] = scv;
            s_sh[t] = be[t] - mean*scv;
        }
        __syncthreads();
    }
    int nl   = t / LPN;
    int q    = (t % LPN)*4;
    int node = blockIdx.x*NODES + nl;
    const __half* hq = h + q;
    float4 sc = make_float4(0,0,0,0), sh = make_float4(0,0,0,0);
    if (BN){ sc = *(const float4*)(s_sc + q); sh = *(const float4*)(s_sh + q); }
    float a0 = 0.f, a1 = 0.f, a2 = 0.f, a3 = 0.f;

    int s = startv[node];
    int e = s + cnt[node];
    for (; s + 8 <= e; s += 8){
        int2 p0 = pairs[s],   p1 = pairs[s+1], p2 = pairs[s+2], p3 = pairs[s+3];
        int2 p4 = pairs[s+4], p5 = pairs[s+5], p6 = pairs[s+6], p7 = pairs[s+7];
        uint2 u0 = *(const uint2*)(hq + (size_t)p0.x*F);
        uint2 u1 = *(const uint2*)(hq + (size_t)p1.x*F);
        uint2 u2v= *(const uint2*)(hq + (size_t)p2.x*F);
        uint2 u3 = *(const uint2*)(hq + (size_t)p3.x*F);
        uint2 u4 = *(const uint2*)(hq + (size_t)p4.x*F);
        uint2 u5 = *(const uint2*)(hq + (size_t)p5.x*F);
        uint2 u6 = *(const uint2*)(hq + (size_t)p6.x*F);
        uint2 u7 = *(const uint2*)(hq + (size_t)p7.x*F);
        acc4<BN>(__int_as_float(p0.y), u0,  sc, sh, a0, a1, a2, a3);
        acc4<BN>(__int_as_float(p1.y), u1,  sc, sh, a0, a1, a2, a3);
        acc4<BN>(__int_as_float(p2.y), u2v, sc, sh, a0, a1, a2, a3);
        acc4<BN>(__int_as_float(p3.y), u3,  sc, sh, a0, a1, a2, a3);
        acc4<BN>(__int_as_float(p4.y), u4,  sc, sh, a0, a1, a2, a3);
        acc4<BN>(__int_as_float(p5.y), u5,  sc, sh, a0, a1, a2, a3);
        acc4<BN>(__int_as_float(p6.y), u6,  sc, sh, a0, a1, a2, a3);
        acc4<BN>(__int_as_float(p7.y), u7,  sc, sh, a0, a1, a2, a3);
    }
    for (; s + 4 <= e; s += 4){
        int2 p0 = pairs[s], p1 = pairs[s+1], p2 = pairs[s+2], p3 = pairs[s+3];
        uint2 u0 = *(const uint2*)(hq + (size_t)p0.x*F);
        uint2 u1 = *(const uint2*)(hq + (size_t)p1.x*F);
        uint2 u2v= *(const uint2*)(hq + (size_t)p2.x*F);
        uint2 u3 = *(const uint2*)(hq + (size_t)p3.x*F);
        acc4<BN>(__int_as_float(p0.y), u0,  sc, sh, a0, a1, a2, a3);
        acc4<BN>(__int_as_float(p1.y), u1,  sc, sh, a0, a1, a2, a3);
        acc4<BN>(__int_as_float(p2.y), u2v, sc, sh, a0, a1, a2, a3);
        acc4<BN>(__int_as_float(p3.y), u3,  sc, sh, a0, a1, a2, a3);
    }
    for (; s < e; ++s){
        int2 p0 = pairs[s];
        uint2 u0 = *(const uint2*)(hq + (size_t)p0.x*F);
        acc4<BN>(__int_as_float(p0.y), u0, sc, sh, a0, a1, a2, a3);
    }
    float di = dinv[node];
    a0 *= di; a1 *= di; a2 *= di; a3 *= di;
    uint2 us = *(const uint2*)(hq + (size_t)node*F);
    acc4<BN>(di*di, us, sc, sh, a0, a1, a2, a3);   // self-loop
    *(uint2*)(&sA[nl][q]) = make_uint2(f2u(a0,a1), f2u(a2,a3));
    __syncthreads();

    int wv = t >> 6, l = t & 63;
    int lr = l & 15, lk = (l >> 4)*8;
    if (F == 64){
        f16x8 af0 = *(const f16x8*)(&sA[lr][lk]);
        f16x8 af1 = *(const f16x8*)(&sA[lr][32 + lk]);
        f16x8 bf0 = *(const f16x8*)(Wh + (size_t)(wv*16 + lr)*64 + lk);
        f16x8 bf1 = *(const f16x8*)(Wh + (size_t)(wv*16 + lr)*64 + 32 + lk);
        f32x4 acc = (f32x4){0.f, 0.f, 0.f, 0.f};
        acc = __builtin_amdgcn_mfma_f32_16x16x32_f16(af0, bf0, acc, 0, 0, 0);
        acc = __builtin_amdgcn_mfma_f32_16x16x32_f16(af1, bf1, acc, 0, 0, 0);
        float bb = bias[wv*16 + lr];
        #pragma unroll
        for (int r = 0; r < 4; ++r)
            sO[(l>>4)*4 + r][wv*16 + lr] = __float2half(acc[r] + bb);
    } else {
        f16x8 bf = *(const f16x8*)(Wh + (size_t)(wv*16 + lr)*32 + lk);
        float bb = bias[wv*16 + lr];
        #pragma unroll
        for (int rt = 0; rt < 2; ++rt){
            f16x8 af = *(const f16x8*)(&sA[rt*16 + lr][lk]);
            f32x4 acc = (f32x4){0.f, 0.f, 0.f, 0.f};
            acc = __builtin_amdgcn_mfma_f32_16x16x32_f16(af, bf, acc, 0, 0, 0);
            #pragma unroll
            for (int r = 0; r < 4; ++r)
                sO[rt*16 + (l>>4)*4 + r][wv*16 + lr] = __float2half(acc[r] + bb);
        }
    }
    __syncthreads();
    int base = blockIdx.x*NODES;
    if (F == 64){
        int rr = t >> 4, cb = (t & 15)*4;
        *(uint2*)(out + (size_t)(base + rr)*64 + cb) = *(const uint2*)(&sO[rr][cb]);
    } else {
        int rr = t >> 3, cb = (t & 7)*8;
        *(uint4*)(out + (size_t)(base + rr)*64 + cb) = *(const uint4*)(&sO[rr][cb]);
    }
}

// ---------------- BN stats over node axis (fp16 input) ----------------
__global__ __launch_bounds__(256) void k_bn_reduce(const __half* __restrict__ x, float* gsum, float* gsq){
    int t = threadIdx.x;
    int f = t & 63, g4 = t >> 6;
    float s = 0.f, q = 0.f;
    for (int i = blockIdx.x*4 + g4; i < N_TOTAL; i += gridDim.x*4){
        float v = __half2float(x[(size_t)i*64 + f]);
        s += v; q += v*v;
    }
    __shared__ float sh[2][4][64];
    sh[0][g4][f] = s; sh[1][g4][f] = q;
    __syncthreads();
    if (t < 64){
        float ss = sh[0][0][t] + sh[0][1][t] + sh[0][2][t] + sh[0][3][t];
        float qq = sh[1][0][t] + sh[1][1][t] + sh[1][2][t] + sh[1][3][t];
        atomicAdd(&gsum[t], ss);
        atomicAdd(&gsq[t],  qq);
    }
}

// ---------------- FC1 on MFMA (bn_final folded into prologue) ----------------
__device__ inline f16x8 bn8(f16x8 v, const float4& s0, const float4& s1,
                            const float4& h0, const float4& h1){
    uint4 u = *(uint4*)&v;
    float2 p0 = u2f(u.x), p1 = u2f(u.y), p2 = u2f(u.z), p3 = u2f(u.w);
    float r0 = fmaxf(0.f, p0.x*s0.x + h0.x);
    float r1 = fmaxf(0.f, p0.y*s0.y + h0.y);
    float r2 = fmaxf(0.f, p1.x*s0.z + h0.z);
    float r3 = fmaxf(0.f, p1.y*s0.w + h0.w);
    float r4 = fmaxf(0.f, p2.x*s1.x + h1.x);
    float r5 = fmaxf(0.f, p2.y*s1.y + h1.y);
    float r6 = fmaxf(0.f, p3.x*s1.z + h1.z);
    float r7 = fmaxf(0.f, p3.y*s1.w + h1.w);
    uint4 o = make_uint4(f2u(r0,r1), f2u(r2,r3), f2u(r4,r5), f2u(r6,r7));
    return *(f16x8*)&o;
}

__global__ __launch_bounds__(256) void k_fc1MF(const __half* __restrict__ A,
                                               const float* __restrict__ Wl1,
                                               const float* __restrict__ gsum,
                                               const float* __restrict__ gsq,
                                               const float* __restrict__ g,
                                               const float* __restrict__ be,
                                               float* __restrict__ part){
    __shared__ __align__(16) __half Bh[128][264];
    __shared__ float s_sc[64], s_sh[64];
    int t = threadIdx.x;
    if (t < 64){
        float mean = gsum[t] * (1.0f/(float)N_TOTAL);
        float var  = gsq[t]  * (1.0f/(float)N_TOTAL) - mean*mean;
        float scv  = g[t] / sqrtf(var + EPS);
        s_sc[t] = scv;
        s_sh[t] = be[t] - mean*scv;
    }
    int kbase = blockIdx.x * FCHUNK;
    #pragma unroll
    for (int i = 0; i < 32; ++i){
        int flat = i*1024 + t*4;
        int r = flat >> 8, k = flat & 255;
        float4 w = *(const float4*)(Wl1 + (size_t)r*FIN + kbase + k);
        *(uint2*)(&Bh[r][k]) = make_uint2(f2u(w.x, w.y), f2u(w.z, w.w));
    }

    int wv = t >> 6, l = t & 63;
    int lr = l & 15, lk = (l >> 4)*8;
    const __half* Ar0 = A + (size_t)(wv*32 + lr)*FIN + kbase + lk;
    const __half* Ar1 = A + (size_t)(wv*32 + 16 + lr)*FIN + kbase + lk;

    f32x4 acc[2][8];
    #pragma unroll
    for (int m = 0; m < 2; ++m)
        #pragma unroll
        for (int n = 0; n < 8; ++n) acc[m][n] = (f32x4){0.f, 0.f, 0.f, 0.f};

    __syncthreads();
    float4 sc_e0 = *(const float4*)(s_sc + lk),      sc_e1 = *(const float4*)(s_sc + lk + 4);
    float4 sc_o0 = *(const float4*)(s_sc + 32 + lk), sc_o1 = *(const float4*)(s_sc + 36 + lk);
    float4 sh_e0 = *(const float4*)(s_sh + lk),      sh_e1 = *(const float4*)(s_sh + lk + 4);
    float4 sh_o0 = *(const float4*)(s_sh + 32 + lk), sh_o1 = *(const float4*)(s_sh + 36 + lk);

    #pragma unroll
    for (int kk = 0; kk < 8; ++kk){
        int ko = kk*32;
        f16x8 a0 = *(const f16x8*)(Ar0 + ko);
        f16x8 a1 = *(const f16x8*)(Ar1 + ko);
        if (kk & 1){
            a0 = bn8(a0, sc_o0, sc_o1, sh_o0, sh_o1);
            a1 = bn8(a1, sc_o0, sc_o1, sh_o0, sh_o1);
        } else {
            a0 = bn8(a0, sc_e0, sc_e1, sh_e0, sh_e1);
            a1 = bn8(a1, sc_e0, sc_e1, sh_e0, sh_e1);
        }
        #pragma unroll
        for (int n = 0; n < 8; ++n){
            f16x8 b = *(const f16x8*)(&Bh[n*16 + lr][ko + lk]);
            acc[0][n] = __builtin_amdgcn_mfma_f32_16x16x32_f16(a0, b, acc[0][n], 0, 0, 0);
            acc[1][n] = __builtin_amdgcn_mfma_f32_16x16x32_f16(a1, b, acc[1][n], 0, 0, 0);
        }
    }
    float* pp = part + (size_t)blockIdx.x*16384;
    #pragma unroll
    for (int m = 0; m < 2; ++m)
        #pragma unroll
        for (int n = 0; n < 8; ++n)
            #pragma unroll
            for (int r = 0; r < 4; ++r)
                pp[(wv*32 + m*16 + (l>>4)*4 + r)*128 + n*16 + lr] = acc[m][n][r];
}

// ---- two-stage split-K reduce ----
__global__ __launch_bounds__(256) void k_fc1_red1(const float* __restrict__ part,
                                                  float* __restrict__ part2){
    int idx = (blockIdx.x & 63)*256 + threadIdx.x;
    int seg = blockIdx.x >> 6;
    int k0 = seg*24;
    int k1 = k0 + 24 < FBLK ? k0 + 24 : FBLK;
    float s = 0.f;
    for (int kc = k0; kc < k1; ++kc) s += part[(size_t)kc*16384 + idx];
    part2[(size_t)seg*16384 + idx] = s;
}

__global__ __launch_bounds__(256) void k_fc1_red2(const float* __restrict__ part2,
                                                  const float* __restrict__ bl1,
                                                  float* __restrict__ C){
    int idx = blockIdx.x*256 + threadIdx.x;
    float s = 0.f;
    #pragma unroll
    for (int i = 0; i < 16; ++i) s += part2[(size_t)i*16384 + idx];
    C[idx] = s + bl1[idx & 127];
}

// ---------------- fused BN stats + FC2 (single block) ----------------
__global__ __launch_bounds__(256) void k_fcTail(const float* __restrict__ C,
                                                const float* __restrict__ gl1,
                                                const float* __restrict__ bel1,
                                                const float* __restrict__ Wl3,
                                                const float* __restrict__ bl3,
                                                float* __restrict__ out){
    __shared__ float ssc[128], ssh[128];
    int t = threadIdx.x;
    if (t < 128){
        float s = 0.f, q = 0.f;
        for (int b = 0; b < 128; ++b){ float v = C[b*128 + t]; s += v; q += v*v; }
        float mean = s / 128.f;
        float var  = q / 128.f - mean*mean;
        float scv  = gl1[t] / sqrtf(var + EPS);
        ssc[t] = scv;
        ssh[t] = bel1[t] - mean*scv;
    }
    __syncthreads();
    for (int id = t; id < 1280; id += 256){
        int b = id / 10, c = id - b*10;
        float acc = bl3[c];
        for (int j = 0; j < 128; ++j){
            float hv = fmaxf(0.f, C[b*128 + j]*ssc[j] + ssh[j]);
            acc += hv * Wl3[c*128 + j];
        }
        out[id] = acc;
    }
}

// ---------------- launch ----------------
extern "C" void kernel_launch(void* const* d_in, const int* in_sizes, int n_in,
                              void* d_out, int out_size, void* d_ws, size_t ws_size,
                              hipStream_t stream){
    const float* x   = (const float*)d_in[0];
    const int*   ei  = (const int*)  d_in[1];
    const float* ew  = (const float*)d_in[2];
    const float* W1  = (const float*)d_in[3];
    const float* b1  = (const float*)d_in[4];
    const float* W2  = (const float*)d_in[5];
    const float* b2  = (const float*)d_in[6];
    const float* W3  = (const float*)d_in[7];
    const float* b3  = (const float*)d_in[8];
    const float* g1  = (const float*)d_in[9];
    const float* be1 = (const float*)d_in[10];
    const float* g2  = (const float*)d_in[11];
    const float* be2 = (const float*)d_in[12];
    const float* g3  = (const float*)d_in[13];
    const float* be3 = (const float*)d_in[14];
    const float* Wl1 = (const float*)d_in[15];
    const float* bl1 = (const float*)d_in[16];
    const float* gl1 = (const float*)d_in[17];
    const float* bel1= (const float*)d_in[18];
    const float* Wl3 = (const float*)d_in[19];
    const float* bl3 = (const float*)d_in[20];
    const int* row = ei;
    const int* col = ei + NE;

    char* p = (char*)d_ws;
    auto alloc = [&](size_t bytes)->char*{
        char* r = p; p += (bytes + 255) & ~(size_t)255; return r;
    };
    int2*   pairsB   = (int2*) alloc((size_t)NBUCK*CAP*8);      // padded bucket regions; aliased FC1 partials
    float*  bufB     = (float*)pairsB;                          // FBLK*16384*4 = 24.8MB <= 31MB
    float*  part2    = (float*)alloc((size_t)16*16384*4);
    __half* hA       = (__half*)alloc((size_t)N_TOTAL*64*2);
    __half* hB       = (__half*)alloc((size_t)N_TOTAL*64*2);
    __half* xh       = (__half*)alloc((size_t)N_TOTAL*32*2);
    float*  dinv     = (float*)alloc(N_TOTAL*4);
    int*    cnt      = (int*)  alloc(N_TOTAL*4);
    int*    startv   = (int*)  alloc(N_TOTAL*4);
    int2*   pairs    = (int2*) alloc((size_t)NBUCK*CAP*8);      // padded node-grouped pairs
    int*    cursor   = (int*)  alloc(NBUCK*4);
    __half* Wh1      = (__half*)alloc(2048*2);
    __half* Wh2      = (__half*)alloc(4096*2);
    __half* Wh3      = (__half*)alloc(4096*2);
    float*  stats    = (float*)alloc(1536);    // 6x64: gsum1,gsq1,gsum2,gsq2,gsum3,gsq3
    float*  Cfc      = (float*)alloc(65536);
    float* gsum1 = stats,        *gsq1 = stats + 64;
    float* gsum2 = stats + 128,  *gsq2 = stats + 192;
    float* gsum3 = stats + 256,  *gsq3 = stats + 320;

    k_prep  <<<758,   256, 0, stream>>>(x, xh, W1, W2, W3, Wh1, Wh2, Wh3, stats, cursor);
    k_bktC2 <<<NBLKC, 256, 0, stream>>>(row, col, ew, cursor, pairsB);
    k_bktD1 <<<NBUCK, 256, 0, stream>>>(pairsB, cursor, startv, cnt, dinv);
    k_bktD2 <<<NBUCK, 256, 0, stream>>>(pairsB, cursor, startv, dinv, pairs);

    // ---- layer 1: fused gather(32)+GEMM -> hA ----
    k_gg<32,false><<<6064,  256, 0, stream>>>(xh, dinv, startv, cnt, pairs,
                                              nullptr, nullptr, nullptr, nullptr, Wh1, b1, hA);
    k_bn_reduce   <<<1024,  256, 0, stream>>>(hA, gsum1, gsq1);
    // ---- layer 2: fused BN1+gather(64)+GEMM -> hB ----
    k_gg<64,true> <<<12128, 256, 0, stream>>>(hA, dinv, startv, cnt, pairs,
                                              gsum1, gsq1, g1, be1, Wh2, b2, hB);
    k_bn_reduce   <<<1024,  256, 0, stream>>>(hB, gsum2, gsq2);
    // ---- layer 3: fused BN2+gather(64)+GEMM -> hA ----
    k_gg<64,true> <<<12128, 256, 0, stream>>>(hB, dinv, startv, cnt, pairs,
                                              gsum2, gsq2, g2, be2, Wh3, b3, hA);
    k_bn_reduce   <<<1024,  256, 0, stream>>>(hA, gsum3, gsq3);

    // ---- FC head (BN3 folded into FC1 prologue; pairsB memory reused as partials) ----
    k_fc1MF    <<<FBLK, 256, 0, stream>>>(hA, Wl1, gsum3, gsq3, g3, be3, bufB);
    k_fc1_red1 <<<1024, 256, 0, stream>>>(bufB, part2);
    k_fc1_red2 <<<64,   256, 0, stream>>>(part2, bl1, Cfc);
    k_fcTail   <<<1,    256, 0, stream>>>(Cfc, gl1, bel1, Wl3, bl3, (float*)d_out);
}